// Round 2
// 139.549 us; speedup vs baseline: 1.2070x; 1.2070x over previous
//
#include <hip/hip_runtime.h>
#include <math.h>

#define BB 16
#define QQ 900
#define CC 92
#define NP 32
#define TT (BB*NP)     // 512
#define RSTRIDE 1024   // LDS cost row stride (floats): 64 lanes x 16 cols
#define NT 512         // round-12: 8 waves/block, 2/SIMD (256-VGPR cap, no spill)

// ---------------------------------------------------------------------------
__device__ __forceinline__ double mkdbl(int lo, int hi) {
    return __longlong_as_double(((long long)hi << 32) | (unsigned int)lo);
}
__device__ __forceinline__ double readlane_dbl(double x, int s) {
    long long l = __double_as_longlong(x);
    int lo = __builtin_amdgcn_readlane((int)l, s);
    int hi = __builtin_amdgcn_readlane((int)(l >> 32), s);
    return mkdbl(lo, hi);
}

// fp64 DPP min step (2 dpp movs + v_min_f64); row_shr:1/2/4/8 + row_bcast:15/31
// leaves the global min in lane 63 (HW-verified rounds 5-9, absmax=0).
#define DPP_MIN64(CTRL)                                                       \
    {                                                                         \
        long long _l = __double_as_longlong(m);                               \
        int _lo = (int)_l, _hi = (int)(_l >> 32);                             \
        int _olo = __builtin_amdgcn_update_dpp(_lo, _lo, CTRL, 0xf, 0xf, false); \
        int _ohi = __builtin_amdgcn_update_dpp(_hi, _hi, CTRL, 0xf, 0xf, false); \
        m = fmin(m, mkdbl(_olo, _ohi));                                       \
    }

// Dynamic LDS partition (bytes)
#define OFF_COST 0
#define SZ_COST  (NP * RSTRIDE * 4)        // 131072
#define OFF_U    (OFF_COST + SZ_COST)      // 33 dbl  -> 264
#define OFF_V    (OFF_U + 264)             // 901 dbl -> 7208
#define OFF_P    (OFF_V + 7208)            // 901 int -> 3604
#define OFF_MAX  (OFF_P + 3604)            // 900 f   -> 3600
#define OFF_SUM  (OFF_MAX + 3600)          // 900 f   -> 3600
#define DYN_BYTES (OFF_SUM + 3600)         // 149348  (< 160 KiB)

// ---------------------------------------------------------------------------
// One block per batch b, 512 threads. Waves 0-7: softmax + cost build into
// LDS; wave 0 alone: the serial reference-_lsa walk; all: float4 epilogue.
//
// Exact reference semantics (established rounds 2-9, absmax=0):
//  * mv == cur algebraically (minv stays ~1e18) -> argmin over unused j of
//    (c - u0) - v0[j] == argmin of key(c - v0[j]); col packed into the key's
//    low 11 bits implements first-occurrence tie-break exactly (perturbation
//    ~1e-11 << key gaps).
//  * deltas recomputed at phase end in EXACT ref order ((c - u0) - v0);
//    u/v replayed with the reference's left-associated per-iteration order.
//
// Round-10: next-row ds_read_b128s issued immediately after ballot/ctz.
// Round-12 changes (bit-exact restructuring only):
//  * NT=256 -> 512: parallel phases (softmax, cost build, epilogue) get 2x
//    issue width + 2x memory-level parallelism at 2 waves/SIMD. Per-element
//    FP order unchanged -> cost bits identical -> identical assignment.
//  * v register-resident in wave 0 (vreg[16]/lane, w-layout). vreg is only
//    written at phase end, so DURING a phase it IS the frozen v0 snapshot
//    the old w[16] copy provided -> w deleted (-32 VGPR).
//  * used-column marking is a 16-bit lane mask ('used'); j1prev -> owning
//    lane/slot via the closed-form inverse of the column map (2 ALU ops vs
//    16 cndmasks). Dead/pad keys forced to 1e300 by cndmask -- same
//    exclusion as the old -1e30 sentinel, same min winner each iteration.
//  * s_u/s_v/s_p de-volatiled: single-wave LDS accesses are HW-ordered;
//    phase-end u/v reads batch into one LDS round-trip.
__launch_bounds__(NT)
__global__ void matcher_kernel(const float* __restrict__ logits,   // (B,Q,C)
                               const float* __restrict__ pboxes,   // (B,Q,4)
                               const int*   __restrict__ labels,   // (T,)
                               const float* __restrict__ tboxes,   // (T,4)
                               float* __restrict__ out)            // (Q,T)
{
    extern __shared__ char smem[];
    float*  s_cost = (float*)(smem + OFF_COST);   // [NP][RSTRIDE]
    double* s_u    = (double*)(smem + OFF_U);
    double* s_v    = (double*)(smem + OFF_V);
    int*    s_p    = (int*)(smem + OFF_P);
    float*  s_max  = (float*)(smem + OFF_MAX);
    float*  s_sum  = (float*)(smem + OFF_SUM);

    const int b   = blockIdx.x;
    const int tid = threadIdx.x;

    // ---- softmax denominators (FP order = rounds 3-9) ---------------------
    const float* lg = logits + (size_t)b * QQ * CC;
    for (int q = tid; q < QQ; q += NT) {
        const float4* row4 = (const float4*)(lg + q * CC);   // 92 = 23 float4
        float mx = -INFINITY;
        #pragma unroll
        for (int k = 0; k < 23; ++k) {
            float4 x = row4[k];
            mx = fmaxf(mx, x.x); mx = fmaxf(mx, x.y);
            mx = fmaxf(mx, x.z); mx = fmaxf(mx, x.w);
        }
        float s = 0.f;
        #pragma unroll
        for (int k = 0; k < 23; ++k) {
            float4 x = row4[k];
            s += expf(x.x - mx); s += expf(x.y - mx);
            s += expf(x.z - mx); s += expf(x.w - mx);
        }
        s_max[q] = mx;
        s_sum[q] = s;
    }
    for (int j = tid; j <= QQ; j += NT) { s_p[j] = 0; s_v[j] = 0.0; }
    if (tid <= NP) s_u[tid] = 0.0;
    __syncthreads();

    // ---- cost matrix -> LDS (FP order identical to rounds 2-9) ------------
    const float* pb = pboxes + (size_t)b * QQ * 4;
    const float* tb = tboxes + (size_t)b * NP * 4;
    const int*   lb = labels + b * NP;
    for (int e = tid; e < NP * QQ; e += NT) {
        int t = e / QQ;
        int q = e - t * QQ;
        float l    = lg[q * CC + lb[t]];
        float prob = expf(l - s_max[q]) / s_sum[q];
        float cclass = -prob;
        float p0 = pb[q*4+0], p1 = pb[q*4+1], p2 = pb[q*4+2], p3 = pb[q*4+3];
        float t0 = tb[t*4+0], t1 = tb[t*4+1], t2 = tb[t*4+2], t3 = tb[t*4+3];
        float cbbox = fabsf(p0-t0) + fabsf(p1-t1) + fabsf(p2-t2) + fabsf(p3-t3);
        float px1 = p0 - 0.5f*p2, py1 = p1 - 0.5f*p3;
        float px2 = p0 + 0.5f*p2, py2 = p1 + 0.5f*p3;
        float tx1 = t0 - 0.5f*t2, ty1 = t1 - 0.5f*t3;
        float tx2 = t0 + 0.5f*t2, ty2 = t1 + 0.5f*t3;
        float area1 = (px2-px1)*(py2-py1);
        float area2 = (tx2-tx1)*(ty2-ty1);
        float ltx = fmaxf(px1,tx1), lty = fmaxf(py1,ty1);
        float rbx = fminf(px2,tx2), rby = fminf(py2,ty2);
        float wx = fmaxf(rbx-ltx, 0.f), wy = fmaxf(rby-lty, 0.f);
        float inter = wx*wy;
        float uni = area1 + area2 - inter;
        float iou = inter / uni;
        float cx1 = fminf(px1,tx1), cy1 = fminf(py1,ty1);
        float cx2 = fmaxf(px2,tx2), cy2 = fmaxf(py2,ty2);
        float cwx = fmaxf(cx2-cx1, 0.f), cwy = fmaxf(cy2-cy1, 0.f);
        float areac = cwx*cwy;
        float giou = iou - (areac - uni) / areac;
        s_cost[t * RSTRIDE + q] = 5.f*cbbox + 1.f*cclass + 2.f*(-giou);
    }
    // zero pad columns 900..1023 (NaN guard for unconditional b128 loads)
    for (int e = tid; e < NP * (RSTRIDE - QQ); e += NT) {
        int row = e / (RSTRIDE - QQ);
        int c   = e - row * (RSTRIDE - QQ);
        s_cost[row * RSTRIDE + QQ + c] = 0.f;
    }
    __syncthreads();

    // ---- the serial walk: WAVE 0 ONLY, barrier-free -----------------------
    if (tid < 64) {
        const int lane = tid;
        int acol = 0;                       // lane r-1: column assigned to row r
        const float4* cbase4 = (const float4*)s_cost;  // 256 float4 per row

        // register-resident v in the w layout: vreg[k] = v[col(k)].
        // Only written at phase end -> during a phase it IS the v0 snapshot.
        double vreg[16];
        #pragma unroll
        for (int k = 0; k < 16; ++k) vreg[k] = 0.0;

        // permanent dead-slot mask for pad columns (col > QQ)
        unsigned used0 = 0;
        #pragma unroll
        for (int k = 0; k < 16; ++k) {
            int col = 4 * lane + ((k >> 2) << 8) + (k & 3) + 1;
            if (col > QQ) used0 |= 1u << k;
        }

        for (int i = 1; i <= NP; ++i) {
            unsigned used = used0;          // per-phase used-column mask

            int i0 = i, j1prev = 0, T = 0;
            int path_reg = 1, row_reg = 1;

            // issue first row's loads before entering the loop
            float4 cf[4];
            {
                const float4* crow4 = cbase4 + (size_t)(i0 - 1) * (RSTRIDE / 4);
                #pragma unroll
                for (int k = 0; k < 4; ++k) cf[k] = crow4[lane + (k << 6)];
            }

            for (int t = 1;; ++t) {
                if (lane == t) row_reg = i0;      // writelane (i0 uniform)
                // mark previous winner used: inverse of the column map
                // col = 4*lane + (k>>2)*256 + (k&3) + 1 ->
                //   owner lane = (q>>2)&63, slot = ((q>>8)<<2)|(q&3), q=col-1
                if (j1prev) {
                    int qp = j1prev - 1;
                    if (((qp >> 2) & 63) == lane)
                        used |= 1u << (((qp >> 8) << 2) | (qp & 3));
                }

                // keys: (c - v0[j]) packed with col in low 11 bits;
                // dead/pad slots forced to 1e300 (never the min)
                double key[16];
                #pragma unroll
                for (int k = 0; k < 4; ++k) {
                    const float* cp = (const float*)&cf[k];
                    #pragma unroll
                    for (int e2 = 0; e2 < 4; ++e2) {
                        int kk  = 4 * k + e2;
                        int col = 4 * lane + (k << 8) + e2 + 1;
                        double d = (double)cp[e2] - vreg[kk];
                        long long bits =
                            (__double_as_longlong(d) & ~2047LL) | (long long)col;
                        key[kk] = ((used >> kk) & 1u)
                                      ? 1e300 : __longlong_as_double(bits);
                    }
                }
                // in-lane 16-way min tree (pure v_min_f64)
                double a0 = fmin(key[0], key[1]),   a1 = fmin(key[2], key[3]);
                double a2 = fmin(key[4], key[5]),   a3 = fmin(key[6], key[7]);
                double a4 = fmin(key[8], key[9]),   a5 = fmin(key[10], key[11]);
                double a6 = fmin(key[12], key[13]), a7 = fmin(key[14], key[15]);
                double b0 = fmin(a0, a1), b1 = fmin(a2, a3);
                double b2 = fmin(a4, a5), b3 = fmin(a6, a7);
                double m  = fmin(fmin(b0, b1), fmin(b2, b3));

                DPP_MIN64(0x111);  // row_shr:1
                DPP_MIN64(0x112);  // row_shr:2
                DPP_MIN64(0x114);  // row_shr:4
                DPP_MIN64(0x118);  // row_shr:8
                DPP_MIN64(0x142);  // row_bcast:15
                DPP_MIN64(0x143);  // row_bcast:31

                int wlo = __builtin_amdgcn_readlane((int)__double_as_longlong(m), 63);
                int j1  = wlo & 2047;

                if (lane == t) path_reg = j1;     // writelane (j1 uniform)

                // p[j1] via ballot over register-resident assignment map
                unsigned long long mask = __ballot(acol == j1);
                if (mask == 0) { T = t; break; }
                int L = (int)__builtin_ctzll(mask);
                i0 = L + 1;
                j1prev = j1;

                // EARLY ISSUE: next row's loads, before next iter's marking
                const float4* crow4 = cbase4 + (size_t)L * (RSTRIDE / 4);
                #pragma unroll
                for (int k = 0; k < 4; ++k) cf[k] = crow4[lane + (k << 6)];
            }

            // ---- phase end: exact ordered replay (lanes 1..T hold r_t, j_t)
            const int  rt  = row_reg;
            const int  myj = path_reg;
            const bool act = (lane >= 1 && lane <= T);
            double mydelta = 0.0, uu = 0.0, vv = 0.0;
            if (act) {
                double cD = (double)s_cost[(rt - 1) * RSTRIDE + (myj - 1)];
                mydelta = (cD - s_u[rt]) - s_v[myj];   // exact ref op order
                uu = s_u[rt];
                vv = s_v[myj];
            }
            for (int s = 1; s <= T; ++s) {
                double ds = readlane_dbl(mydelta, s);
                int    js = __builtin_amdgcn_readlane(path_reg, s);
                int    rs = __builtin_amdgcn_readlane(row_reg, s);
                if (lane >= 1 && lane <= s) uu += ds;   // u[r_t] += d_t..d_T
                if (lane >= 1 && lane <  s) vv -= ds;   // v[j_t] -= d_{t+1}..d_T
                if (rs == lane + 1) acol = js;          // row r_s now on col j_s
            }
            if (act) {
                s_u[rt]  = uu;
                s_v[myj] = vv;
                s_p[myj] = rt;
            }
            // mirror this phase's v updates into vreg (compile-time indices
            // only -- runtime-indexed arrays would spill to scratch)
            for (int s = 1; s <= T; ++s) {
                int    js  = __builtin_amdgcn_readlane(path_reg, s);
                double vvs = readlane_dbl(vv, s);
                #pragma unroll
                for (int k = 0; k < 16; ++k) {
                    int col = 4 * lane + ((k >> 2) << 8) + (k & 3) + 1;
                    if (col == js) vreg[k] = vvs;
                }
            }
        }
    }
    __syncthreads();

    // ---- epilogue: full (900 x 32) tile, float4 stores --------------------
    for (int e = tid; e < QQ * 8; e += NT) {
        int q = e >> 3;
        int f = e & 7;
        int pq = s_p[q + 1];
        int base = 4 * f;
        float4 o;
        o.x = (pq == base + 1) ? 1.f : 0.f;
        o.y = (pq == base + 2) ? 1.f : 0.f;
        o.z = (pq == base + 3) ? 1.f : 0.f;
        o.w = (pq == base + 4) ? 1.f : 0.f;
        ((float4*)(out + (size_t)q * TT + b * NP))[f] = o;
    }
}

// ---------------------------------------------------------------------------
extern "C" void kernel_launch(void* const* d_in, const int* in_sizes, int n_in,
                              void* d_out, int out_size, void* d_ws, size_t ws_size,
                              hipStream_t stream) {
    const float* logits = (const float*)d_in[0];   // (16,900,92)
    const float* pboxes = (const float*)d_in[1];   // (16,900,4)
    const int*   labels = (const int*)  d_in[2];   // (512,)
    const float* tboxes = (const float*)d_in[3];   // (512,4)
    float* out = (float*)d_out;                    // (900,512) fp32

    (void)hipFuncSetAttribute((const void*)matcher_kernel,
                              hipFuncAttributeMaxDynamicSharedMemorySize,
                              DYN_BYTES);

    matcher_kernel<<<BB, NT, DYN_BYTES, stream>>>(logits, pboxes, labels,
                                                  tboxes, out);
}

// Round 3
// 120.245 us; speedup vs baseline: 1.4007x; 1.1605x over previous
//
#include <hip/hip_runtime.h>
#include <math.h>

#define BB 16
#define QQ 900
#define CC 92
#define NP 32
#define TT (BB*NP)     // 512
#define RSTRIDE 1024   // LDS cost row stride (floats): 64 lanes x 16 cols
#define NT 512         // 8 waves/block, 2/SIMD

// ---------------------------------------------------------------------------
__device__ __forceinline__ double mkdbl(int lo, int hi) {
    return __longlong_as_double(((long long)hi << 32) | (unsigned int)lo);
}
__device__ __forceinline__ double readlane_dbl(double x, int s) {
    long long l = __double_as_longlong(x);
    int lo = __builtin_amdgcn_readlane((int)l, s);
    int hi = __builtin_amdgcn_readlane((int)(l >> 32), s);
    return mkdbl(lo, hi);
}

// fp64 DPP min step (2 dpp movs + v_min_f64); row_shr:1/2/4/8 + row_bcast:15/31
// leaves the global min in lane 63 (HW-verified rounds 5-9, absmax=0).
#define DPP_MIN64(CTRL)                                                       \
    {                                                                         \
        long long _l = __double_as_longlong(m);                               \
        int _lo = (int)_l, _hi = (int)(_l >> 32);                             \
        int _olo = __builtin_amdgcn_update_dpp(_lo, _lo, CTRL, 0xf, 0xf, false); \
        int _ohi = __builtin_amdgcn_update_dpp(_hi, _hi, CTRL, 0xf, 0xf, false); \
        m = fmin(m, mkdbl(_olo, _ohi));                                       \
    }

// Dynamic LDS partition (bytes)
#define OFF_COST 0
#define SZ_COST  (NP * RSTRIDE * 4)        // 131072
#define OFF_U    (OFF_COST + SZ_COST)      // 33 dbl  -> 264
#define OFF_V    (OFF_U + 264)             // 901 dbl -> 7208
#define OFF_P    (OFF_V + 7208)            // 901 int -> 3604
#define OFF_MAX  (OFF_P + 3604)            // 900 f   -> 3600
#define OFF_SUM  (OFF_MAX + 3600)          // 900 f   -> 3600
#define OFF_FLAG (OFF_SUM + 3600)          // 32 int  -> 128
#define DYN_BYTES (OFF_FLAG + 128)         // 149476  (< 160 KiB)

// ---------------------------------------------------------------------------
// One block per batch b, 512 threads.
// Round-13 (scheduling-only change; every FP op bit-identical to round 12):
//   all waves: softmax denominators -> __syncthreads ->
//   waves 1-7: build cost rows round-robin (wave w owns rows w-1, w-1+7, ...),
//              publish per-row ready flags (lgkmcnt(0) drain before flag);
//   wave 0   : init u/v/p, then the serial JV walk. Walk phase i only touches
//              rows 1..i, so it waits (s_sleep spin, monotone counter) only
//              until flags 0..i-1 are set -> cost build hides under the walk.
//   all waves: __syncthreads -> float4 epilogue.
//
// Exact reference semantics (established rounds 2-9, absmax=0):
//  * argmin over unused j of (c - u0) - v0[j] == argmin of key(c - v0[j]);
//    col packed into the key's low 11 bits implements first-occurrence
//    tie-break exactly (perturbation ~1e-11 << key gaps).
//  * deltas recomputed at phase end in EXACT ref order ((c - u0) - v0);
//    u/v replayed with the reference's left-associated per-iteration order.
// Round-12 walk core kept verbatim: vreg[16] register-resident v (w-layout,
// written only at phase end -> doubles as the frozen v0 snapshot), 16-bit
// used-column mask with closed-form owner test, non-volatile s_u/s_v/s_p.
__launch_bounds__(NT)
__global__ void matcher_kernel(const float* __restrict__ logits,   // (B,Q,C)
                               const float* __restrict__ pboxes,   // (B,Q,4)
                               const int*   __restrict__ labels,   // (T,)
                               const float* __restrict__ tboxes,   // (T,4)
                               float* __restrict__ out)            // (Q,T)
{
    extern __shared__ char smem[];
    float*  s_cost = (float*)(smem + OFF_COST);   // [NP][RSTRIDE]
    double* s_u    = (double*)(smem + OFF_U);
    double* s_v    = (double*)(smem + OFF_V);
    int*    s_p    = (int*)(smem + OFF_P);
    float*  s_max  = (float*)(smem + OFF_MAX);
    float*  s_sum  = (float*)(smem + OFF_SUM);
    volatile int* s_flag = (volatile int*)(smem + OFF_FLAG);

    const int b    = blockIdx.x;
    const int tid  = threadIdx.x;
    const int wv   = tid >> 6;
    const int lane = tid & 63;

    // ---- softmax denominators, all 8 waves (FP order = rounds 3-9) --------
    const float* lg = logits + (size_t)b * QQ * CC;
    if (tid < 32) s_flag[tid] = 0;
    for (int q = tid; q < QQ; q += NT) {
        const float4* row4 = (const float4*)(lg + q * CC);   // 92 = 23 float4
        float mx = -INFINITY;
        #pragma unroll
        for (int k = 0; k < 23; ++k) {
            float4 x = row4[k];
            mx = fmaxf(mx, x.x); mx = fmaxf(mx, x.y);
            mx = fmaxf(mx, x.z); mx = fmaxf(mx, x.w);
        }
        float s = 0.f;
        #pragma unroll
        for (int k = 0; k < 23; ++k) {
            float4 x = row4[k];
            s += expf(x.x - mx); s += expf(x.y - mx);
            s += expf(x.z - mx); s += expf(x.w - mx);
        }
        s_max[q] = mx;
        s_sum[q] = s;
    }
    __syncthreads();

    const float* pb = pboxes + (size_t)b * QQ * 4;
    const float* tb = tboxes + (size_t)b * NP * 4;
    const int*   lb = labels + b * NP;

    if (wv != 0) {
        // ---- waves 1-7: cost rows round-robin, flag after lgkmcnt drain ---
        // (per-element formula bit-identical to rounds 2-12; pads q>=900 = 0)
        for (int t = wv - 1; t < NP; t += 7) {
            const float t0 = tb[t*4+0], t1 = tb[t*4+1],
                        t2 = tb[t*4+2], t3 = tb[t*4+3];
            const int   lt = lb[t];
            const float tx1 = t0 - 0.5f*t2, ty1 = t1 - 0.5f*t3;
            const float tx2 = t0 + 0.5f*t2, ty2 = t1 + 0.5f*t3;
            const float area2 = (tx2-tx1)*(ty2-ty1);
            #pragma unroll 4
            for (int it = 0; it < 16; ++it) {
                int q = (it << 6) + lane;           // 0..1023
                float val = 0.f;
                if (q < QQ) {
                    float l    = lg[q * CC + lt];
                    float prob = expf(l - s_max[q]) / s_sum[q];
                    float cclass = -prob;
                    float p0 = pb[q*4+0], p1 = pb[q*4+1],
                          p2 = pb[q*4+2], p3 = pb[q*4+3];
                    float cbbox = fabsf(p0-t0) + fabsf(p1-t1)
                                + fabsf(p2-t2) + fabsf(p3-t3);
                    float px1 = p0 - 0.5f*p2, py1 = p1 - 0.5f*p3;
                    float px2 = p0 + 0.5f*p2, py2 = p1 + 0.5f*p3;
                    float area1 = (px2-px1)*(py2-py1);
                    float ltx = fmaxf(px1,tx1), lty = fmaxf(py1,ty1);
                    float rbx = fminf(px2,tx2), rby = fminf(py2,ty2);
                    float wx = fmaxf(rbx-ltx, 0.f), wy = fmaxf(rby-lty, 0.f);
                    float inter = wx*wy;
                    float uni = area1 + area2 - inter;
                    float iou = inter / uni;
                    float cx1 = fminf(px1,tx1), cy1 = fminf(py1,ty1);
                    float cx2 = fmaxf(px2,tx2), cy2 = fmaxf(py2,ty2);
                    float cwx = fmaxf(cx2-cx1, 0.f), cwy = fmaxf(cy2-cy1, 0.f);
                    float areac = cwx*cwy;
                    float giou = iou - (areac - uni) / areac;
                    val = 5.f*cbbox + 1.f*cclass + 2.f*(-giou);
                }
                s_cost[t * RSTRIDE + q] = val;
            }
            // all ds_writes of this row drained before the flag is visible
            asm volatile("s_waitcnt lgkmcnt(0)" ::: "memory");
            if (lane == 0) s_flag[t] = 1;
        }
    } else {
        // ---- wave 0: init u/v/p, then the serial walk ---------------------
        for (int j = lane; j <= QQ; j += 64) { s_p[j] = 0; s_v[j] = 0.0; }
        if (lane <= NP) s_u[lane] = 0.0;
        asm volatile("s_waitcnt lgkmcnt(0)" ::: "memory");

        int acol = 0;                       // lane r-1: column assigned to row r
        const float4* cbase4 = (const float4*)s_cost;  // 256 float4 per row

        // register-resident v in the w layout: vreg[k] = v[col(k)].
        // Only written at phase end -> during a phase it IS the v0 snapshot.
        double vreg[16];
        #pragma unroll
        for (int k = 0; k < 16; ++k) vreg[k] = 0.0;

        // permanent dead-slot mask for pad columns (col > QQ)
        unsigned used0 = 0;
        #pragma unroll
        for (int k = 0; k < 16; ++k) {
            int col = 4 * lane + ((k >> 2) << 8) + (k & 3) + 1;
            if (col > QQ) used0 |= 1u << k;
        }

        int nv = 0;                         // rows verified ready (monotone)
        for (int i = 1; i <= NP; ++i) {
            // wait until rows 0..i-1 are published
            while (nv < i) {
                if (s_flag[nv]) ++nv;
                else __builtin_amdgcn_s_sleep(2);
            }

            unsigned used = used0;          // per-phase used-column mask

            int i0 = i, j1prev = 0, T = 0;
            int path_reg = 1, row_reg = 1;

            // issue first row's loads before entering the loop
            float4 cf[4];
            {
                const float4* crow4 = cbase4 + (size_t)(i0 - 1) * (RSTRIDE / 4);
                #pragma unroll
                for (int k = 0; k < 4; ++k) cf[k] = crow4[lane + (k << 6)];
            }

            for (int t = 1;; ++t) {
                if (lane == t) row_reg = i0;      // writelane (i0 uniform)
                // mark previous winner used: inverse of the column map
                // col = 4*lane + (k>>2)*256 + (k&3) + 1 ->
                //   owner lane = (q>>2)&63, slot = ((q>>8)<<2)|(q&3), q=col-1
                if (j1prev) {
                    int qp = j1prev - 1;
                    if (((qp >> 2) & 63) == lane)
                        used |= 1u << (((qp >> 8) << 2) | (qp & 3));
                }

                // keys: (c - v0[j]) packed with col in low 11 bits;
                // dead/pad slots forced to 1e300 (never the min)
                double key[16];
                #pragma unroll
                for (int k = 0; k < 4; ++k) {
                    const float* cp = (const float*)&cf[k];
                    #pragma unroll
                    for (int e2 = 0; e2 < 4; ++e2) {
                        int kk  = 4 * k + e2;
                        int col = 4 * lane + (k << 8) + e2 + 1;
                        double d = (double)cp[e2] - vreg[kk];
                        long long bits =
                            (__double_as_longlong(d) & ~2047LL) | (long long)col;
                        key[kk] = ((used >> kk) & 1u)
                                      ? 1e300 : __longlong_as_double(bits);
                    }
                }
                // in-lane 16-way min tree (pure v_min_f64)
                double a0 = fmin(key[0], key[1]),   a1 = fmin(key[2], key[3]);
                double a2 = fmin(key[4], key[5]),   a3 = fmin(key[6], key[7]);
                double a4 = fmin(key[8], key[9]),   a5 = fmin(key[10], key[11]);
                double a6 = fmin(key[12], key[13]), a7 = fmin(key[14], key[15]);
                double b0 = fmin(a0, a1), b1 = fmin(a2, a3);
                double b2 = fmin(a4, a5), b3 = fmin(a6, a7);
                double m  = fmin(fmin(b0, b1), fmin(b2, b3));

                DPP_MIN64(0x111);  // row_shr:1
                DPP_MIN64(0x112);  // row_shr:2
                DPP_MIN64(0x114);  // row_shr:4
                DPP_MIN64(0x118);  // row_shr:8
                DPP_MIN64(0x142);  // row_bcast:15
                DPP_MIN64(0x143);  // row_bcast:31

                int wlo = __builtin_amdgcn_readlane((int)__double_as_longlong(m), 63);
                int j1  = wlo & 2047;

                if (lane == t) path_reg = j1;     // writelane (j1 uniform)

                // p[j1] via ballot over register-resident assignment map
                unsigned long long mask = __ballot(acol == j1);
                if (mask == 0) { T = t; break; }
                int L = (int)__builtin_ctzll(mask);
                i0 = L + 1;
                j1prev = j1;

                // EARLY ISSUE: next row's loads, before next iter's marking
                const float4* crow4 = cbase4 + (size_t)L * (RSTRIDE / 4);
                #pragma unroll
                for (int k = 0; k < 4; ++k) cf[k] = crow4[lane + (k << 6)];
            }

            // ---- phase end: exact ordered replay (lanes 1..T hold r_t, j_t)
            const int  rt  = row_reg;
            const int  myj = path_reg;
            const bool act = (lane >= 1 && lane <= T);
            double mydelta = 0.0, uu = 0.0, vv = 0.0;
            if (act) {
                double cD = (double)s_cost[(rt - 1) * RSTRIDE + (myj - 1)];
                mydelta = (cD - s_u[rt]) - s_v[myj];   // exact ref op order
                uu = s_u[rt];
                vv = s_v[myj];
            }
            for (int s = 1; s <= T; ++s) {
                double ds = readlane_dbl(mydelta, s);
                int    js = __builtin_amdgcn_readlane(path_reg, s);
                int    rs = __builtin_amdgcn_readlane(row_reg, s);
                if (lane >= 1 && lane <= s) uu += ds;   // u[r_t] += d_t..d_T
                if (lane >= 1 && lane <  s) vv -= ds;   // v[j_t] -= d_{t+1}..d_T
                if (rs == lane + 1) acol = js;          // row r_s now on col j_s
            }
            if (act) {
                s_u[rt]  = uu;
                s_v[myj] = vv;
                s_p[myj] = rt;
            }
            // mirror this phase's v updates into vreg (compile-time indices
            // only -- runtime-indexed arrays would spill to scratch)
            for (int s = 1; s <= T; ++s) {
                int    js  = __builtin_amdgcn_readlane(path_reg, s);
                double vvs = readlane_dbl(vv, s);
                #pragma unroll
                for (int k = 0; k < 16; ++k) {
                    int col = 4 * lane + ((k >> 2) << 8) + (k & 3) + 1;
                    if (col == js) vreg[k] = vvs;
                }
            }
        }
    }
    __syncthreads();

    // ---- epilogue: full (900 x 32) tile, float4 stores --------------------
    for (int e = tid; e < QQ * 8; e += NT) {
        int q = e >> 3;
        int f = e & 7;
        int pq = s_p[q + 1];
        int base = 4 * f;
        float4 o;
        o.x = (pq == base + 1) ? 1.f : 0.f;
        o.y = (pq == base + 2) ? 1.f : 0.f;
        o.z = (pq == base + 3) ? 1.f : 0.f;
        o.w = (pq == base + 4) ? 1.f : 0.f;
        ((float4*)(out + (size_t)q * TT + b * NP))[f] = o;
    }
}

// ---------------------------------------------------------------------------
extern "C" void kernel_launch(void* const* d_in, const int* in_sizes, int n_in,
                              void* d_out, int out_size, void* d_ws, size_t ws_size,
                              hipStream_t stream) {
    const float* logits = (const float*)d_in[0];   // (16,900,92)
    const float* pboxes = (const float*)d_in[1];   // (16,900,4)
    const int*   labels = (const int*)  d_in[2];   // (512,)
    const float* tboxes = (const float*)d_in[3];   // (512,4)
    float* out = (float*)d_out;                    // (900,512) fp32

    (void)hipFuncSetAttribute((const void*)matcher_kernel,
                              hipFuncAttributeMaxDynamicSharedMemorySize,
                              DYN_BYTES);

    matcher_kernel<<<BB, NT, DYN_BYTES, stream>>>(logits, pboxes, labels,
                                                  tboxes, out);
}

// Round 4
// 116.919 us; speedup vs baseline: 1.4406x; 1.0284x over previous
//
#include <hip/hip_runtime.h>
#include <math.h>

#define BB 16
#define QQ 900
#define CC 92
#define NP 32
#define TT (BB*NP)     // 512
#define RSTRIDE 1024   // cost row stride (floats)
#define NT 512         // monolithic fallback: 8 waves/block

// ---------------------------------------------------------------------------
// Workspace layout (bytes)
#define WSC_COST 0
#define WSC_MAX  (BB*NP*RSTRIDE*4)          // 512 rows * 4KB = 2097152
#define WSC_SUM  (WSC_MAX + BB*QQ*4)        // + 57600
#define WSC_A    (WSC_SUM + BB*QQ*4)        // + 57600
#define WS_NEED  (WSC_A + TT*4)             // + 2048 = 2214400

// ---------------------------------------------------------------------------
__device__ __forceinline__ double mkdbl(int lo, int hi) {
    return __longlong_as_double(((long long)hi << 32) | (unsigned int)lo);
}
__device__ __forceinline__ double readlane_dbl(double x, int s) {
    long long l = __double_as_longlong(x);
    int lo = __builtin_amdgcn_readlane((int)l, s);
    int hi = __builtin_amdgcn_readlane((int)(l >> 32), s);
    return mkdbl(lo, hi);
}

// fp64 DPP min step (2 dpp movs + v_min_f64); row_shr:1/2/4/8 + row_bcast:15/31
// leaves the global min in lane 63 (HW-verified rounds 5-9, absmax=0).
#define DPP_MIN64(CTRL)                                                       \
    {                                                                         \
        long long _l = __double_as_longlong(m);                               \
        int _lo = (int)_l, _hi = (int)(_l >> 32);                             \
        int _olo = __builtin_amdgcn_update_dpp(_lo, _lo, CTRL, 0xf, 0xf, false); \
        int _ohi = __builtin_amdgcn_update_dpp(_hi, _hi, CTRL, 0xf, 0xf, false); \
        m = fmin(m, mkdbl(_olo, _ohi));                                       \
    }

// ===========================================================================
// Kernel A: softmax denominators, full chip. One thread per (b,q) row;
// per-row FP chain byte-identical to the monolithic softmax loop.
__launch_bounds__(256)
__global__ void denom_kernel(const float* __restrict__ logits,
                             float* __restrict__ wmax,
                             float* __restrict__ wsum)
{
    int idx = blockIdx.x * 256 + threadIdx.x;
    if (idx >= BB * QQ) return;
    const float4* row4 = (const float4*)(logits + (size_t)idx * CC);
    float mx = -INFINITY;
    #pragma unroll
    for (int k = 0; k < 23; ++k) {
        float4 x = row4[k];
        mx = fmaxf(mx, x.x); mx = fmaxf(mx, x.y);
        mx = fmaxf(mx, x.z); mx = fmaxf(mx, x.w);
    }
    float s = 0.f;
    #pragma unroll
    for (int k = 0; k < 23; ++k) {
        float4 x = row4[k];
        s += expf(x.x - mx); s += expf(x.y - mx);
        s += expf(x.z - mx); s += expf(x.w - mx);
    }
    wmax[idx] = mx;
    wsum[idx] = s;
}

// ===========================================================================
// Kernel B: cost rows, full chip. One block per (b,t); per-element FP
// formula byte-identical to rounds 2-13. Pads q in [900,1024) = 0.
__launch_bounds__(256)
__global__ void cost_kernel(const float* __restrict__ logits,
                            const float* __restrict__ pboxes,
                            const int*   __restrict__ labels,
                            const float* __restrict__ tboxes,
                            const float* __restrict__ wmax,
                            const float* __restrict__ wsum,
                            float* __restrict__ wcost)
{
    const int r = blockIdx.x;          // 0..511 = b*NP + t
    const int b = r >> 5, t = r & 31;
    const float* lg = logits + (size_t)b * QQ * CC;
    const float* pb = pboxes + (size_t)b * QQ * 4;
    const float* tb = tboxes + (size_t)b * NP * 4;
    const float* smax = wmax + b * QQ;
    const float* ssum = wsum + b * QQ;

    const float t0 = tb[t*4+0], t1 = tb[t*4+1], t2 = tb[t*4+2], t3 = tb[t*4+3];
    const int   lt = labels[b * NP + t];
    const float tx1 = t0 - 0.5f*t2, ty1 = t1 - 0.5f*t3;
    const float tx2 = t0 + 0.5f*t2, ty2 = t1 + 0.5f*t3;
    const float area2 = (tx2-tx1)*(ty2-ty1);

    float* crow = wcost + (size_t)r * RSTRIDE;
    for (int q = threadIdx.x; q < RSTRIDE; q += 256) {
        float val = 0.f;
        if (q < QQ) {
            float l    = lg[q * CC + lt];
            float prob = expf(l - smax[q]) / ssum[q];
            float cclass = -prob;
            float p0 = pb[q*4+0], p1 = pb[q*4+1], p2 = pb[q*4+2], p3 = pb[q*4+3];
            float cbbox = fabsf(p0-t0) + fabsf(p1-t1)
                        + fabsf(p2-t2) + fabsf(p3-t3);
            float px1 = p0 - 0.5f*p2, py1 = p1 - 0.5f*p3;
            float px2 = p0 + 0.5f*p2, py2 = p1 + 0.5f*p3;
            float area1 = (px2-px1)*(py2-py1);
            float ltx = fmaxf(px1,tx1), lty = fmaxf(py1,ty1);
            float rbx = fminf(px2,tx2), rby = fminf(py2,ty2);
            float wx = fmaxf(rbx-ltx, 0.f), wy = fmaxf(rby-lty, 0.f);
            float inter = wx*wy;
            float uni = area1 + area2 - inter;
            float iou = inter / uni;
            float cx1 = fminf(px1,tx1), cy1 = fminf(py1,ty1);
            float cx2 = fmaxf(px2,tx2), cy2 = fmaxf(py2,ty2);
            float cwx = fmaxf(cx2-cx1, 0.f), cwy = fmaxf(cy2-cy1, 0.f);
            float areac = cwx*cwy;
            float giou = iou - (areac - uni) / areac;
            val = 5.f*cbbox + 1.f*cclass + 2.f*(-giou);
        }
        crow[q] = val;
    }
}

// ===========================================================================
// Kernel C: the serial JV walk (verbatim round-13 core). 16 blocks x 4 waves:
// waves 1-3 stage cost rows ws->LDS round-robin with per-row flags; wave 0
// inits u/v, spins flags monotonically, walks, writes the 32 assigned
// columns (0-based q) to wa[b*NP + row].
#define C_OFF_COST 0
#define C_SZ_COST  (NP * RSTRIDE * 4)       // 131072
#define C_OFF_U    (C_OFF_COST + C_SZ_COST) // 33 dbl  -> 264
#define C_OFF_V    (C_OFF_U + 264)          // 901 dbl -> 7208
#define C_OFF_FLAG (C_OFF_V + 7208)         // 32 int  -> 128
#define C_DYN      (C_OFF_FLAG + 128)       // 138672  (< 160 KiB)

__launch_bounds__(256)
__global__ void walk_kernel(const float* __restrict__ wcost,
                            int* __restrict__ wa)
{
    extern __shared__ char smem[];
    float*  s_cost = (float*)(smem + C_OFF_COST);   // [NP][RSTRIDE]
    double* s_u    = (double*)(smem + C_OFF_U);
    double* s_v    = (double*)(smem + C_OFF_V);
    volatile int* s_flag = (volatile int*)(smem + C_OFF_FLAG);

    const int b    = blockIdx.x;
    const int tid  = threadIdx.x;
    const int wv   = tid >> 6;
    const int lane = tid & 63;

    if (tid < 32) s_flag[tid] = 0;
    __syncthreads();

    if (wv != 0) {
        // ---- waves 1-3: stage rows round-robin, flag after full drain -----
        for (int t = wv - 1; t < NP; t += 3) {
            const float4* src =
                (const float4*)(wcost + ((size_t)(b * NP + t) * RSTRIDE));
            float4* dst = (float4*)(s_cost + t * RSTRIDE);
            float4 v0 = src[lane];
            float4 v1 = src[lane + 64];
            float4 v2 = src[lane + 128];
            float4 v3 = src[lane + 192];
            dst[lane]       = v0;
            dst[lane + 64]  = v1;
            dst[lane + 128] = v2;
            dst[lane + 192] = v3;
            asm volatile("s_waitcnt vmcnt(0) lgkmcnt(0)" ::: "memory");
            if (lane == 0) s_flag[t] = 1;
        }
        return;
    }

    // ---- wave 0: init u/v, then the serial walk ---------------------------
    for (int j = lane; j <= QQ; j += 64) s_v[j] = 0.0;
    if (lane <= NP) s_u[lane] = 0.0;
    asm volatile("s_waitcnt lgkmcnt(0)" ::: "memory");

    int acol = 0;                       // lane r-1: column assigned to row r
    const float4* cbase4 = (const float4*)s_cost;  // 256 float4 per row

    // register-resident v in the w layout: vreg[k] = v[col(k)].
    // Only written at phase end -> during a phase it IS the v0 snapshot.
    double vreg[16];
    #pragma unroll
    for (int k = 0; k < 16; ++k) vreg[k] = 0.0;

    // permanent dead-slot mask for pad columns (col > QQ)
    unsigned used0 = 0;
    #pragma unroll
    for (int k = 0; k < 16; ++k) {
        int col = 4 * lane + ((k >> 2) << 8) + (k & 3) + 1;
        if (col > QQ) used0 |= 1u << k;
    }

    int nv = 0;                         // rows verified ready (monotone)
    for (int i = 1; i <= NP; ++i) {
        // wait until rows 0..i-1 are published
        while (nv < i) {
            if (s_flag[nv]) ++nv;
            else __builtin_amdgcn_s_sleep(2);
        }

        unsigned used = used0;          // per-phase used-column mask

        int i0 = i, j1prev = 0, T = 0;
        int path_reg = 1, row_reg = 1;

        // issue first row's loads before entering the loop
        float4 cf[4];
        {
            const float4* crow4 = cbase4 + (size_t)(i0 - 1) * (RSTRIDE / 4);
            #pragma unroll
            for (int k = 0; k < 4; ++k) cf[k] = crow4[lane + (k << 6)];
        }

        for (int t = 1;; ++t) {
            if (lane == t) row_reg = i0;      // writelane (i0 uniform)
            // mark previous winner used: inverse of the column map
            // col = 4*lane + (k>>2)*256 + (k&3) + 1 ->
            //   owner lane = (q>>2)&63, slot = ((q>>8)<<2)|(q&3), q=col-1
            if (j1prev) {
                int qp = j1prev - 1;
                if (((qp >> 2) & 63) == lane)
                    used |= 1u << (((qp >> 8) << 2) | (qp & 3));
            }

            // keys: (c - v0[j]) packed with col in low 11 bits;
            // dead/pad slots forced to 1e300 (never the min)
            double key[16];
            #pragma unroll
            for (int k = 0; k < 4; ++k) {
                const float* cp = (const float*)&cf[k];
                #pragma unroll
                for (int e2 = 0; e2 < 4; ++e2) {
                    int kk  = 4 * k + e2;
                    int col = 4 * lane + (k << 8) + e2 + 1;
                    double d = (double)cp[e2] - vreg[kk];
                    long long bits =
                        (__double_as_longlong(d) & ~2047LL) | (long long)col;
                    key[kk] = ((used >> kk) & 1u)
                                  ? 1e300 : __longlong_as_double(bits);
                }
            }
            // in-lane 16-way min tree (pure v_min_f64)
            double a0 = fmin(key[0], key[1]),   a1 = fmin(key[2], key[3]);
            double a2 = fmin(key[4], key[5]),   a3 = fmin(key[6], key[7]);
            double a4 = fmin(key[8], key[9]),   a5 = fmin(key[10], key[11]);
            double a6 = fmin(key[12], key[13]), a7 = fmin(key[14], key[15]);
            double b0 = fmin(a0, a1), b1 = fmin(a2, a3);
            double b2 = fmin(a4, a5), b3 = fmin(a6, a7);
            double m  = fmin(fmin(b0, b1), fmin(b2, b3));

            DPP_MIN64(0x111);  // row_shr:1
            DPP_MIN64(0x112);  // row_shr:2
            DPP_MIN64(0x114);  // row_shr:4
            DPP_MIN64(0x118);  // row_shr:8
            DPP_MIN64(0x142);  // row_bcast:15
            DPP_MIN64(0x143);  // row_bcast:31

            int wlo = __builtin_amdgcn_readlane((int)__double_as_longlong(m), 63);
            int j1  = wlo & 2047;

            if (lane == t) path_reg = j1;     // writelane (j1 uniform)

            // p[j1] via ballot over register-resident assignment map
            unsigned long long mask = __ballot(acol == j1);
            if (mask == 0) { T = t; break; }
            int L = (int)__builtin_ctzll(mask);
            i0 = L + 1;
            j1prev = j1;

            // EARLY ISSUE: next row's loads, before next iter's marking
            const float4* crow4 = cbase4 + (size_t)L * (RSTRIDE / 4);
            #pragma unroll
            for (int k = 0; k < 4; ++k) cf[k] = crow4[lane + (k << 6)];
        }

        // ---- phase end: exact ordered replay (lanes 1..T hold r_t, j_t) ---
        const int  rt  = row_reg;
        const int  myj = path_reg;
        const bool act = (lane >= 1 && lane <= T);
        double mydelta = 0.0, uu = 0.0, vv = 0.0;
        if (act) {
            double cD = (double)s_cost[(rt - 1) * RSTRIDE + (myj - 1)];
            mydelta = (cD - s_u[rt]) - s_v[myj];   // exact ref op order
            uu = s_u[rt];
            vv = s_v[myj];
        }
        for (int s = 1; s <= T; ++s) {
            double ds = readlane_dbl(mydelta, s);
            int    js = __builtin_amdgcn_readlane(path_reg, s);
            int    rs = __builtin_amdgcn_readlane(row_reg, s);
            if (lane >= 1 && lane <= s) uu += ds;   // u[r_t] += d_t..d_T
            if (lane >= 1 && lane <  s) vv -= ds;   // v[j_t] -= d_{t+1}..d_T
            if (rs == lane + 1) acol = js;          // row r_s now on col j_s
        }
        if (act) {
            s_u[rt]  = uu;
            s_v[myj] = vv;
        }
        // mirror this phase's v updates into vreg (compile-time indices
        // only -- runtime-indexed arrays would spill to scratch)
        for (int s = 1; s <= T; ++s) {
            int    js  = __builtin_amdgcn_readlane(path_reg, s);
            double vvs = readlane_dbl(vv, s);
            #pragma unroll
            for (int k = 0; k < 16; ++k) {
                int col = 4 * lane + ((k >> 2) << 8) + (k & 3) + 1;
                if (col == js) vreg[k] = vvs;
            }
        }
    }

    // lanes 0..31 hold acol = 1-based column of row lane+1
    if (lane < NP) wa[b * NP + lane] = acol - 1;
}

// ===========================================================================
// Kernel D: epilogue, full chip. out[q][b*NP+t] = (wa[b*NP+t] == q).
__launch_bounds__(256)
__global__ void epilogue_kernel(const int* __restrict__ wa,
                                float* __restrict__ out)
{
    int idx = blockIdx.x * 256 + threadIdx.x;    // < QQ*BB*8 = 115200
    if (idx >= QQ * BB * 8) return;
    int q   = idx >> 7;          // /128
    int rem = idx & 127;
    int b   = rem >> 3, f = rem & 7;
    int base = b * NP + 4 * f;
    int a0 = wa[base + 0], a1 = wa[base + 1];
    int a2 = wa[base + 2], a3 = wa[base + 3];
    float4 o;
    o.x = (a0 == q) ? 1.f : 0.f;
    o.y = (a1 == q) ? 1.f : 0.f;
    o.z = (a2 == q) ? 1.f : 0.f;
    o.w = (a3 == q) ? 1.f : 0.f;
    ((float4*)(out + (size_t)q * TT + b * NP))[f] = o;
}

// ===========================================================================
// Fallback: the round-13 monolithic kernel, verbatim (used if ws too small).
#define OFF_COST 0
#define SZ_COST  (NP * RSTRIDE * 4)        // 131072
#define OFF_U    (OFF_COST + SZ_COST)      // 33 dbl  -> 264
#define OFF_V    (OFF_U + 264)             // 901 dbl -> 7208
#define OFF_P    (OFF_V + 7208)            // 901 int -> 3604
#define OFF_MAX  (OFF_P + 3604)            // 900 f   -> 3600
#define OFF_SUM  (OFF_MAX + 3600)          // 900 f   -> 3600
#define OFF_FLAG (OFF_SUM + 3600)          // 32 int  -> 128
#define DYN_BYTES (OFF_FLAG + 128)         // 149476  (< 160 KiB)

__launch_bounds__(NT)
__global__ void matcher_kernel(const float* __restrict__ logits,
                               const float* __restrict__ pboxes,
                               const int*   __restrict__ labels,
                               const float* __restrict__ tboxes,
                               float* __restrict__ out)
{
    extern __shared__ char smem[];
    float*  s_cost = (float*)(smem + OFF_COST);
    double* s_u    = (double*)(smem + OFF_U);
    double* s_v    = (double*)(smem + OFF_V);
    int*    s_p    = (int*)(smem + OFF_P);
    float*  s_max  = (float*)(smem + OFF_MAX);
    float*  s_sum  = (float*)(smem + OFF_SUM);
    volatile int* s_flag = (volatile int*)(smem + OFF_FLAG);

    const int b    = blockIdx.x;
    const int tid  = threadIdx.x;
    const int wv   = tid >> 6;
    const int lane = tid & 63;

    const float* lg = logits + (size_t)b * QQ * CC;
    if (tid < 32) s_flag[tid] = 0;
    for (int q = tid; q < QQ; q += NT) {
        const float4* row4 = (const float4*)(lg + q * CC);
        float mx = -INFINITY;
        #pragma unroll
        for (int k = 0; k < 23; ++k) {
            float4 x = row4[k];
            mx = fmaxf(mx, x.x); mx = fmaxf(mx, x.y);
            mx = fmaxf(mx, x.z); mx = fmaxf(mx, x.w);
        }
        float s = 0.f;
        #pragma unroll
        for (int k = 0; k < 23; ++k) {
            float4 x = row4[k];
            s += expf(x.x - mx); s += expf(x.y - mx);
            s += expf(x.z - mx); s += expf(x.w - mx);
        }
        s_max[q] = mx;
        s_sum[q] = s;
    }
    __syncthreads();

    const float* pb = pboxes + (size_t)b * QQ * 4;
    const float* tb = tboxes + (size_t)b * NP * 4;
    const int*   lb = labels + b * NP;

    if (wv != 0) {
        for (int t = wv - 1; t < NP; t += 7) {
            const float t0 = tb[t*4+0], t1 = tb[t*4+1],
                        t2 = tb[t*4+2], t3 = tb[t*4+3];
            const int   lt = lb[t];
            const float tx1 = t0 - 0.5f*t2, ty1 = t1 - 0.5f*t3;
            const float tx2 = t0 + 0.5f*t2, ty2 = t1 + 0.5f*t3;
            const float area2 = (tx2-tx1)*(ty2-ty1);
            #pragma unroll 4
            for (int it = 0; it < 16; ++it) {
                int q = (it << 6) + lane;
                float val = 0.f;
                if (q < QQ) {
                    float l    = lg[q * CC + lt];
                    float prob = expf(l - s_max[q]) / s_sum[q];
                    float cclass = -prob;
                    float p0 = pb[q*4+0], p1 = pb[q*4+1],
                          p2 = pb[q*4+2], p3 = pb[q*4+3];
                    float cbbox = fabsf(p0-t0) + fabsf(p1-t1)
                                + fabsf(p2-t2) + fabsf(p3-t3);
                    float px1 = p0 - 0.5f*p2, py1 = p1 - 0.5f*p3;
                    float px2 = p0 + 0.5f*p2, py2 = p1 + 0.5f*p3;
                    float area1 = (px2-px1)*(py2-py1);
                    float ltx = fmaxf(px1,tx1), lty = fmaxf(py1,ty1);
                    float rbx = fminf(px2,tx2), rby = fminf(py2,ty2);
                    float wx = fmaxf(rbx-ltx, 0.f), wy = fmaxf(rby-lty, 0.f);
                    float inter = wx*wy;
                    float uni = area1 + area2 - inter;
                    float iou = inter / uni;
                    float cx1 = fminf(px1,tx1), cy1 = fminf(py1,ty1);
                    float cx2 = fmaxf(px2,tx2), cy2 = fmaxf(py2,ty2);
                    float cwx = fmaxf(cx2-cx1, 0.f), cwy = fmaxf(cy2-cy1, 0.f);
                    float areac = cwx*cwy;
                    float giou = iou - (areac - uni) / areac;
                    val = 5.f*cbbox + 1.f*cclass + 2.f*(-giou);
                }
                s_cost[t * RSTRIDE + q] = val;
            }
            asm volatile("s_waitcnt lgkmcnt(0)" ::: "memory");
            if (lane == 0) s_flag[t] = 1;
        }
    } else {
        for (int j = lane; j <= QQ; j += 64) { s_p[j] = 0; s_v[j] = 0.0; }
        if (lane <= NP) s_u[lane] = 0.0;
        asm volatile("s_waitcnt lgkmcnt(0)" ::: "memory");

        int acol = 0;
        const float4* cbase4 = (const float4*)s_cost;

        double vreg[16];
        #pragma unroll
        for (int k = 0; k < 16; ++k) vreg[k] = 0.0;

        unsigned used0 = 0;
        #pragma unroll
        for (int k = 0; k < 16; ++k) {
            int col = 4 * lane + ((k >> 2) << 8) + (k & 3) + 1;
            if (col > QQ) used0 |= 1u << k;
        }

        int nv = 0;
        for (int i = 1; i <= NP; ++i) {
            while (nv < i) {
                if (s_flag[nv]) ++nv;
                else __builtin_amdgcn_s_sleep(2);
            }
            unsigned used = used0;
            int i0 = i, j1prev = 0, T = 0;
            int path_reg = 1, row_reg = 1;
            float4 cf[4];
            {
                const float4* crow4 = cbase4 + (size_t)(i0 - 1) * (RSTRIDE / 4);
                #pragma unroll
                for (int k = 0; k < 4; ++k) cf[k] = crow4[lane + (k << 6)];
            }
            for (int t = 1;; ++t) {
                if (lane == t) row_reg = i0;
                if (j1prev) {
                    int qp = j1prev - 1;
                    if (((qp >> 2) & 63) == lane)
                        used |= 1u << (((qp >> 8) << 2) | (qp & 3));
                }
                double key[16];
                #pragma unroll
                for (int k = 0; k < 4; ++k) {
                    const float* cp = (const float*)&cf[k];
                    #pragma unroll
                    for (int e2 = 0; e2 < 4; ++e2) {
                        int kk  = 4 * k + e2;
                        int col = 4 * lane + (k << 8) + e2 + 1;
                        double d = (double)cp[e2] - vreg[kk];
                        long long bits =
                            (__double_as_longlong(d) & ~2047LL) | (long long)col;
                        key[kk] = ((used >> kk) & 1u)
                                      ? 1e300 : __longlong_as_double(bits);
                    }
                }
                double a0 = fmin(key[0], key[1]),   a1 = fmin(key[2], key[3]);
                double a2 = fmin(key[4], key[5]),   a3 = fmin(key[6], key[7]);
                double a4 = fmin(key[8], key[9]),   a5 = fmin(key[10], key[11]);
                double a6 = fmin(key[12], key[13]), a7 = fmin(key[14], key[15]);
                double b0 = fmin(a0, a1), b1 = fmin(a2, a3);
                double b2 = fmin(a4, a5), b3 = fmin(a6, a7);
                double m  = fmin(fmin(b0, b1), fmin(b2, b3));
                DPP_MIN64(0x111); DPP_MIN64(0x112); DPP_MIN64(0x114);
                DPP_MIN64(0x118); DPP_MIN64(0x142); DPP_MIN64(0x143);
                int wlo = __builtin_amdgcn_readlane((int)__double_as_longlong(m), 63);
                int j1  = wlo & 2047;
                if (lane == t) path_reg = j1;
                unsigned long long mask = __ballot(acol == j1);
                if (mask == 0) { T = t; break; }
                int L = (int)__builtin_ctzll(mask);
                i0 = L + 1;
                j1prev = j1;
                const float4* crow4 = cbase4 + (size_t)L * (RSTRIDE / 4);
                #pragma unroll
                for (int k = 0; k < 4; ++k) cf[k] = crow4[lane + (k << 6)];
            }
            const int  rt  = row_reg;
            const int  myj = path_reg;
            const bool act = (lane >= 1 && lane <= T);
            double mydelta = 0.0, uu = 0.0, vv = 0.0;
            if (act) {
                double cD = (double)s_cost[(rt - 1) * RSTRIDE + (myj - 1)];
                mydelta = (cD - s_u[rt]) - s_v[myj];
                uu = s_u[rt];
                vv = s_v[myj];
            }
            for (int s = 1; s <= T; ++s) {
                double ds = readlane_dbl(mydelta, s);
                int    js = __builtin_amdgcn_readlane(path_reg, s);
                int    rs = __builtin_amdgcn_readlane(row_reg, s);
                if (lane >= 1 && lane <= s) uu += ds;
                if (lane >= 1 && lane <  s) vv -= ds;
                if (rs == lane + 1) acol = js;
            }
            if (act) {
                s_u[rt]  = uu;
                s_v[myj] = vv;
                s_p[myj] = rt;
            }
            for (int s = 1; s <= T; ++s) {
                int    js  = __builtin_amdgcn_readlane(path_reg, s);
                double vvs = readlane_dbl(vv, s);
                #pragma unroll
                for (int k = 0; k < 16; ++k) {
                    int col = 4 * lane + ((k >> 2) << 8) + (k & 3) + 1;
                    if (col == js) vreg[k] = vvs;
                }
            }
        }
    }
    __syncthreads();

    for (int e = tid; e < QQ * 8; e += NT) {
        int q = e >> 3;
        int f = e & 7;
        int pq = s_p[q + 1];
        int base = 4 * f;
        float4 o;
        o.x = (pq == base + 1) ? 1.f : 0.f;
        o.y = (pq == base + 2) ? 1.f : 0.f;
        o.z = (pq == base + 3) ? 1.f : 0.f;
        o.w = (pq == base + 4) ? 1.f : 0.f;
        ((float4*)(out + (size_t)q * TT + b * NP))[f] = o;
    }
}

// ---------------------------------------------------------------------------
extern "C" void kernel_launch(void* const* d_in, const int* in_sizes, int n_in,
                              void* d_out, int out_size, void* d_ws, size_t ws_size,
                              hipStream_t stream) {
    const float* logits = (const float*)d_in[0];   // (16,900,92)
    const float* pboxes = (const float*)d_in[1];   // (16,900,4)
    const int*   labels = (const int*)  d_in[2];   // (512,)
    const float* tboxes = (const float*)d_in[3];   // (512,4)
    float* out = (float*)d_out;                    // (900,512) fp32

    if (d_ws != nullptr && ws_size >= (size_t)WS_NEED) {
        float* wcost = (float*)((char*)d_ws + WSC_COST);
        float* wmax  = (float*)((char*)d_ws + WSC_MAX);
        float* wsum  = (float*)((char*)d_ws + WSC_SUM);
        int*   wa    = (int*)  ((char*)d_ws + WSC_A);

        (void)hipFuncSetAttribute((const void*)walk_kernel,
                                  hipFuncAttributeMaxDynamicSharedMemorySize,
                                  C_DYN);

        denom_kernel<<<(BB*QQ + 255)/256, 256, 0, stream>>>(logits, wmax, wsum);
        cost_kernel<<<BB*NP, 256, 0, stream>>>(logits, pboxes, labels, tboxes,
                                               wmax, wsum, wcost);
        walk_kernel<<<BB, 256, C_DYN, stream>>>(wcost, wa);
        epilogue_kernel<<<(QQ*BB*8 + 255)/256, 256, 0, stream>>>(wa, out);
    } else {
        (void)hipFuncSetAttribute((const void*)matcher_kernel,
                                  hipFuncAttributeMaxDynamicSharedMemorySize,
                                  DYN_BYTES);
        matcher_kernel<<<BB, NT, DYN_BYTES, stream>>>(logits, pboxes, labels,
                                                      tboxes, out);
    }
}

// Round 5
// 105.293 us; speedup vs baseline: 1.5997x; 1.1104x over previous
//
#include <hip/hip_runtime.h>
#include <math.h>

#define BB 16
#define QQ 900
#define CC 92
#define NP 32
#define TT (BB*NP)     // 512
#define RSTRIDE 1024   // cost row stride (floats)
#define NT 512         // monolithic fallback: 8 waves/block

// ---------------------------------------------------------------------------
// Workspace layout (bytes)
#define WSC_COST 0
#define WSC_MAX  (BB*NP*RSTRIDE*4)          // 512 rows * 4KB = 2097152
#define WSC_SUM  (WSC_MAX + BB*QQ*4)        // + 57600
#define WSC_A    (WSC_SUM + BB*QQ*4)        // + 57600
#define WS_NEED  (WSC_A + TT*4)             // + 2048 = 2214400

// ---------------------------------------------------------------------------
__device__ __forceinline__ double mkdbl(int lo, int hi) {
    return __longlong_as_double(((long long)hi << 32) | (unsigned int)lo);
}
__device__ __forceinline__ double readlane_dbl(double x, int s) {
    long long l = __double_as_longlong(x);
    int lo = __builtin_amdgcn_readlane((int)l, s);
    int hi = __builtin_amdgcn_readlane((int)(l >> 32), s);
    return mkdbl(lo, hi);
}

// fp64 DPP min step (2 dpp movs + v_min_f64); row_shr:1/2/4/8 + row_bcast:15/31
// leaves the global min in lane 63 (HW-verified rounds 5-9, absmax=0).
#define DPP_MIN64(CTRL)                                                       \
    {                                                                         \
        long long _l = __double_as_longlong(m);                               \
        int _lo = (int)_l, _hi = (int)(_l >> 32);                             \
        int _olo = __builtin_amdgcn_update_dpp(_lo, _lo, CTRL, 0xf, 0xf, false); \
        int _ohi = __builtin_amdgcn_update_dpp(_hi, _hi, CTRL, 0xf, 0xf, false); \
        m = fmin(m, mkdbl(_olo, _ohi));                                       \
    }

// ===========================================================================
// Kernel A: softmax denominators, full chip. One thread per (b,q) row;
// per-row FP chain byte-identical to the monolithic softmax loop.
__launch_bounds__(256)
__global__ void denom_kernel(const float* __restrict__ logits,
                             float* __restrict__ wmax,
                             float* __restrict__ wsum)
{
    int idx = blockIdx.x * 256 + threadIdx.x;
    if (idx >= BB * QQ) return;
    const float4* row4 = (const float4*)(logits + (size_t)idx * CC);
    float mx = -INFINITY;
    #pragma unroll
    for (int k = 0; k < 23; ++k) {
        float4 x = row4[k];
        mx = fmaxf(mx, x.x); mx = fmaxf(mx, x.y);
        mx = fmaxf(mx, x.z); mx = fmaxf(mx, x.w);
    }
    float s = 0.f;
    #pragma unroll
    for (int k = 0; k < 23; ++k) {
        float4 x = row4[k];
        s += expf(x.x - mx); s += expf(x.y - mx);
        s += expf(x.z - mx); s += expf(x.w - mx);
    }
    wmax[idx] = mx;
    wsum[idx] = s;
}

// ===========================================================================
// Kernel B: cost rows, full chip. One block per (b,t); per-element FP
// formula byte-identical to rounds 2-13. Pads q in [900,1024) = 0.
__launch_bounds__(256)
__global__ void cost_kernel(const float* __restrict__ logits,
                            const float* __restrict__ pboxes,
                            const int*   __restrict__ labels,
                            const float* __restrict__ tboxes,
                            const float* __restrict__ wmax,
                            const float* __restrict__ wsum,
                            float* __restrict__ wcost)
{
    const int r = blockIdx.x;          // 0..511 = b*NP + t
    const int b = r >> 5, t = r & 31;
    const float* lg = logits + (size_t)b * QQ * CC;
    const float* pb = pboxes + (size_t)b * QQ * 4;
    const float* tb = tboxes + (size_t)b * NP * 4;
    const float* smax = wmax + b * QQ;
    const float* ssum = wsum + b * QQ;

    const float t0 = tb[t*4+0], t1 = tb[t*4+1], t2 = tb[t*4+2], t3 = tb[t*4+3];
    const int   lt = labels[b * NP + t];
    const float tx1 = t0 - 0.5f*t2, ty1 = t1 - 0.5f*t3;
    const float tx2 = t0 + 0.5f*t2, ty2 = t1 + 0.5f*t3;
    const float area2 = (tx2-tx1)*(ty2-ty1);

    float* crow = wcost + (size_t)r * RSTRIDE;
    for (int q = threadIdx.x; q < RSTRIDE; q += 256) {
        float val = 0.f;
        if (q < QQ) {
            float l    = lg[q * CC + lt];
            float prob = expf(l - smax[q]) / ssum[q];
            float cclass = -prob;
            float p0 = pb[q*4+0], p1 = pb[q*4+1], p2 = pb[q*4+2], p3 = pb[q*4+3];
            float cbbox = fabsf(p0-t0) + fabsf(p1-t1)
                        + fabsf(p2-t2) + fabsf(p3-t3);
            float px1 = p0 - 0.5f*p2, py1 = p1 - 0.5f*p3;
            float px2 = p0 + 0.5f*p2, py2 = p1 + 0.5f*p3;
            float area1 = (px2-px1)*(py2-py1);
            float ltx = fmaxf(px1,tx1), lty = fmaxf(py1,ty1);
            float rbx = fminf(px2,tx2), rby = fminf(py2,ty2);
            float wx = fmaxf(rbx-ltx, 0.f), wy = fmaxf(rby-lty, 0.f);
            float inter = wx*wy;
            float uni = area1 + area2 - inter;
            float iou = inter / uni;
            float cx1 = fminf(px1,tx1), cy1 = fminf(py1,ty1);
            float cx2 = fmaxf(px2,tx2), cy2 = fmaxf(py2,ty2);
            float cwx = fmaxf(cx2-cx1, 0.f), cwy = fmaxf(cy2-cy1, 0.f);
            float areac = cwx*cwy;
            float giou = iou - (areac - uni) / areac;
            val = 5.f*cbbox + 1.f*cclass + 2.f*(-giou);
        }
        crow[q] = val;
    }
}

// ===========================================================================
// Kernel C: the serial JV walk. 16 blocks x 4 waves: waves 1-3 stage cost
// rows ws->LDS round-robin with per-row flags; wave 0 inits u/v, walks,
// writes the 32 assigned columns (0-based q) to wa[b*NP + row].
//
// Round-15 inner-loop changes (exclusion winner provably identical):
//  * used-mask + per-slot 1e300 cndmask DELETED. Exclusion folded into vreg:
//    pads init to -1e300; a column that becomes j1prev has its owner slot's
//    vreg[k] corrupted to -1e300 (16 compile-time cmp+cndmask, only when
//    j1prev!=0). d = c - vreg is then finite ~+1e300..DBL_MAX > any valid
//    key (~1e4) -> same argmin winner bit-for-bit. The phase-end mirror
//    rewrites exactly the path columns (superset of corrupted slots) with
//    the correct new v, repairing vreg before the next phase.
//  * next phase's first row (index i, known in advance) pre-issued BEFORE
//    the phase-end replay when its ready-flag is already set (one-time
//    all-staged fast path: flags 29&30&31 together imply rows 0..31 staged
//    given the 3-wave round-robin t = wv-1 + 3k).
#define C_OFF_COST 0
#define C_SZ_COST  (NP * RSTRIDE * 4)       // 131072
#define C_OFF_U    (C_OFF_COST + C_SZ_COST) // 33 dbl  -> 264
#define C_OFF_V    (C_OFF_U + 264)          // 901 dbl -> 7208
#define C_OFF_FLAG (C_OFF_V + 7208)         // 32 int  -> 128
#define C_DYN      (C_OFF_FLAG + 128)       // 138672  (< 160 KiB)

__launch_bounds__(256)
__global__ void walk_kernel(const float* __restrict__ wcost,
                            int* __restrict__ wa)
{
    extern __shared__ char smem[];
    float*  s_cost = (float*)(smem + C_OFF_COST);   // [NP][RSTRIDE]
    double* s_u    = (double*)(smem + C_OFF_U);
    double* s_v    = (double*)(smem + C_OFF_V);
    volatile int* s_flag = (volatile int*)(smem + C_OFF_FLAG);

    const int b    = blockIdx.x;
    const int tid  = threadIdx.x;
    const int wv   = tid >> 6;
    const int lane = tid & 63;

    if (tid < 32) s_flag[tid] = 0;
    __syncthreads();

    if (wv != 0) {
        // ---- waves 1-3: stage rows round-robin, flag after full drain -----
        for (int t = wv - 1; t < NP; t += 3) {
            const float4* src =
                (const float4*)(wcost + ((size_t)(b * NP + t) * RSTRIDE));
            float4* dst = (float4*)(s_cost + t * RSTRIDE);
            float4 v0 = src[lane];
            float4 v1 = src[lane + 64];
            float4 v2 = src[lane + 128];
            float4 v3 = src[lane + 192];
            dst[lane]       = v0;
            dst[lane + 64]  = v1;
            dst[lane + 128] = v2;
            dst[lane + 192] = v3;
            asm volatile("s_waitcnt vmcnt(0) lgkmcnt(0)" ::: "memory");
            if (lane == 0) s_flag[t] = 1;
        }
        return;
    }

    // ---- wave 0: init u/v, then the serial walk ---------------------------
    for (int j = lane; j <= QQ; j += 64) s_v[j] = 0.0;
    if (lane <= NP) s_u[lane] = 0.0;
    asm volatile("s_waitcnt lgkmcnt(0)" ::: "memory");

    int acol = 0;                       // lane r-1: column assigned to row r
    const float4* cbase4 = (const float4*)s_cost;  // 256 float4 per row

    // register-resident v in the w layout: vreg[k] = v[col(k)].
    // Pads (col > QQ) held at -1e300 forever (excluded; never repaired
    // since path cols are always <= QQ). Written only at phase end ->
    // during a phase it IS the frozen v0 snapshot.
    double vreg[16];
    #pragma unroll
    for (int k = 0; k < 16; ++k) {
        int col = 4 * lane + ((k >> 2) << 8) + (k & 3) + 1;
        vreg[k] = (col <= QQ) ? 0.0 : -1.0e300;
    }

    int nv = 0;                         // rows verified ready (monotone)

    // prologue: wait for row 0, load phase-1's row
    while (nv < 1) {
        if (s_flag[0]) nv = 1;
        else __builtin_amdgcn_s_sleep(2);
    }
    float4 cf[4];
    {
        const float4* crow4 = cbase4;   // row 0
        #pragma unroll
        for (int k = 0; k < 4; ++k) cf[k] = crow4[lane + (k << 6)];
    }

    for (int i = 1; i <= NP; ++i) {
        // cf already holds row i-1 (phase's starting row)
        int i0 = i, j1prev = 0, T = 0;
        int path_reg = 1, row_reg = 1;

        for (int t = 1;; ++t) {
            if (lane == t) row_reg = i0;      // writelane (i0 uniform)
            // mark previous winner used by corrupting its vreg slot to
            // -1e300 (skipped when j1prev==0 -- wave-uniform branch).
            // Repaired by the phase-end mirror (j1prev cols are path cols).
            if (j1prev) {
                #pragma unroll
                for (int k = 0; k < 16; ++k) {
                    int col = 4 * lane + ((k >> 2) << 8) + (k & 3) + 1;
                    if (col == j1prev) vreg[k] = -1.0e300;
                }
            }

            // keys: (c - v0[j]) packed with col in low 11 bits; excluded
            // slots (pads + used) give finite ~+1e300..DBL_MAX -> never min
            double key[16];
            #pragma unroll
            for (int k = 0; k < 4; ++k) {
                const float* cp = (const float*)&cf[k];
                #pragma unroll
                for (int e2 = 0; e2 < 4; ++e2) {
                    int kk  = 4 * k + e2;
                    int col = 4 * lane + (k << 8) + e2 + 1;
                    double d = (double)cp[e2] - vreg[kk];
                    long long bits =
                        (__double_as_longlong(d) & ~2047LL) | (long long)col;
                    key[kk] = __longlong_as_double(bits);
                }
            }
            // in-lane 16-way min tree (pure v_min_f64)
            double a0 = fmin(key[0], key[1]),   a1 = fmin(key[2], key[3]);
            double a2 = fmin(key[4], key[5]),   a3 = fmin(key[6], key[7]);
            double a4 = fmin(key[8], key[9]),   a5 = fmin(key[10], key[11]);
            double a6 = fmin(key[12], key[13]), a7 = fmin(key[14], key[15]);
            double b0 = fmin(a0, a1), b1 = fmin(a2, a3);
            double b2 = fmin(a4, a5), b3 = fmin(a6, a7);
            double m  = fmin(fmin(b0, b1), fmin(b2, b3));

            DPP_MIN64(0x111);  // row_shr:1
            DPP_MIN64(0x112);  // row_shr:2
            DPP_MIN64(0x114);  // row_shr:4
            DPP_MIN64(0x118);  // row_shr:8
            DPP_MIN64(0x142);  // row_bcast:15
            DPP_MIN64(0x143);  // row_bcast:31

            int wlo = __builtin_amdgcn_readlane((int)__double_as_longlong(m), 63);
            int j1  = wlo & 2047;

            if (lane == t) path_reg = j1;     // writelane (j1 uniform)

            // p[j1] via ballot over register-resident assignment map
            unsigned long long mask = __ballot(acol == j1);
            if (mask == 0) { T = t; break; }
            int L = (int)__builtin_ctzll(mask);
            i0 = L + 1;
            j1prev = j1;

            // EARLY ISSUE: next row's loads, before next iter's marking
            const float4* crow4 = cbase4 + (size_t)L * (RSTRIDE / 4);
            #pragma unroll
            for (int k = 0; k < 4; ++k) cf[k] = crow4[lane + (k << 6)];
        }

        // ---- pre-issue next phase's row (index i) if already staged -------
        bool pre = false;
        if (i < NP) {
            if (nv > i) pre = true;
            else if (s_flag[29] && s_flag[30] && s_flag[31]) {
                nv = NP;            // 3-wave round-robin: these imply all 32
                pre = true;
            }
            if (pre) {
                const float4* crow4 = cbase4 + (size_t)i * (RSTRIDE / 4);
                #pragma unroll
                for (int k = 0; k < 4; ++k) cf[k] = crow4[lane + (k << 6)];
            }
        }

        // ---- phase end: exact ordered replay (lanes 1..T hold r_t, j_t) ---
        const int  rt  = row_reg;
        const int  myj = path_reg;
        const bool act = (lane >= 1 && lane <= T);
        double mydelta = 0.0, uu = 0.0, vv = 0.0;
        if (act) {
            double cD = (double)s_cost[(rt - 1) * RSTRIDE + (myj - 1)];
            mydelta = (cD - s_u[rt]) - s_v[myj];   // exact ref op order
            uu = s_u[rt];
            vv = s_v[myj];
        }
        for (int s = 1; s <= T; ++s) {
            double ds = readlane_dbl(mydelta, s);
            int    js = __builtin_amdgcn_readlane(path_reg, s);
            int    rs = __builtin_amdgcn_readlane(row_reg, s);
            if (lane >= 1 && lane <= s) uu += ds;   // u[r_t] += d_t..d_T
            if (lane >= 1 && lane <  s) vv -= ds;   // v[j_t] -= d_{t+1}..d_T
            if (rs == lane + 1) acol = js;          // row r_s now on col j_s
        }
        if (act) {
            s_u[rt]  = uu;
            s_v[myj] = vv;
        }
        // mirror this phase's v updates into vreg (repairs corrupted slots;
        // compile-time indices only -- runtime indexing would spill)
        for (int s = 1; s <= T; ++s) {
            int    js  = __builtin_amdgcn_readlane(path_reg, s);
            double vvs = readlane_dbl(vv, s);
            #pragma unroll
            for (int k = 0; k < 16; ++k) {
                int col = 4 * lane + ((k >> 2) << 8) + (k & 3) + 1;
                if (col == js) vreg[k] = vvs;
            }
        }

        // ---- deferred load path (row i not staged yet at pre-check) -------
        if (i < NP && !pre) {
            while (nv <= i) {
                if (s_flag[nv]) ++nv;
                else __builtin_amdgcn_s_sleep(2);
            }
            const float4* crow4 = cbase4 + (size_t)i * (RSTRIDE / 4);
            #pragma unroll
            for (int k = 0; k < 4; ++k) cf[k] = crow4[lane + (k << 6)];
        }
    }

    // lanes 0..31 hold acol = 1-based column of row lane+1
    if (lane < NP) wa[b * NP + lane] = acol - 1;
}

// ===========================================================================
// Kernel D: epilogue, full chip. out[q][b*NP+t] = (wa[b*NP+t] == q).
__launch_bounds__(256)
__global__ void epilogue_kernel(const int* __restrict__ wa,
                                float* __restrict__ out)
{
    int idx = blockIdx.x * 256 + threadIdx.x;    // < QQ*BB*8 = 115200
    if (idx >= QQ * BB * 8) return;
    int q   = idx >> 7;          // /128
    int rem = idx & 127;
    int b   = rem >> 3, f = rem & 7;
    int base = b * NP + 4 * f;
    int a0 = wa[base + 0], a1 = wa[base + 1];
    int a2 = wa[base + 2], a3 = wa[base + 3];
    float4 o;
    o.x = (a0 == q) ? 1.f : 0.f;
    o.y = (a1 == q) ? 1.f : 0.f;
    o.z = (a2 == q) ? 1.f : 0.f;
    o.w = (a3 == q) ? 1.f : 0.f;
    ((float4*)(out + (size_t)q * TT + b * NP))[f] = o;
}

// ===========================================================================
// Fallback: the round-13 monolithic kernel, verbatim (used if ws too small).
#define OFF_COST 0
#define SZ_COST  (NP * RSTRIDE * 4)        // 131072
#define OFF_U    (OFF_COST + SZ_COST)      // 33 dbl  -> 264
#define OFF_V    (OFF_U + 264)             // 901 dbl -> 7208
#define OFF_P    (OFF_V + 7208)            // 901 int -> 3604
#define OFF_MAX  (OFF_P + 3604)            // 900 f   -> 3600
#define OFF_SUM  (OFF_MAX + 3600)          // 900 f   -> 3600
#define OFF_FLAG (OFF_SUM + 3600)          // 32 int  -> 128
#define DYN_BYTES (OFF_FLAG + 128)         // 149476  (< 160 KiB)

__launch_bounds__(NT)
__global__ void matcher_kernel(const float* __restrict__ logits,
                               const float* __restrict__ pboxes,
                               const int*   __restrict__ labels,
                               const float* __restrict__ tboxes,
                               float* __restrict__ out)
{
    extern __shared__ char smem[];
    float*  s_cost = (float*)(smem + OFF_COST);
    double* s_u    = (double*)(smem + OFF_U);
    double* s_v    = (double*)(smem + OFF_V);
    int*    s_p    = (int*)(smem + OFF_P);
    float*  s_max  = (float*)(smem + OFF_MAX);
    float*  s_sum  = (float*)(smem + OFF_SUM);
    volatile int* s_flag = (volatile int*)(smem + OFF_FLAG);

    const int b    = blockIdx.x;
    const int tid  = threadIdx.x;
    const int wv   = tid >> 6;
    const int lane = tid & 63;

    const float* lg = logits + (size_t)b * QQ * CC;
    if (tid < 32) s_flag[tid] = 0;
    for (int q = tid; q < QQ; q += NT) {
        const float4* row4 = (const float4*)(lg + q * CC);
        float mx = -INFINITY;
        #pragma unroll
        for (int k = 0; k < 23; ++k) {
            float4 x = row4[k];
            mx = fmaxf(mx, x.x); mx = fmaxf(mx, x.y);
            mx = fmaxf(mx, x.z); mx = fmaxf(mx, x.w);
        }
        float s = 0.f;
        #pragma unroll
        for (int k = 0; k < 23; ++k) {
            float4 x = row4[k];
            s += expf(x.x - mx); s += expf(x.y - mx);
            s += expf(x.z - mx); s += expf(x.w - mx);
        }
        s_max[q] = mx;
        s_sum[q] = s;
    }
    __syncthreads();

    const float* pb = pboxes + (size_t)b * QQ * 4;
    const float* tb = tboxes + (size_t)b * NP * 4;
    const int*   lb = labels + b * NP;

    if (wv != 0) {
        for (int t = wv - 1; t < NP; t += 7) {
            const float t0 = tb[t*4+0], t1 = tb[t*4+1],
                        t2 = tb[t*4+2], t3 = tb[t*4+3];
            const int   lt = lb[t];
            const float tx1 = t0 - 0.5f*t2, ty1 = t1 - 0.5f*t3;
            const float tx2 = t0 + 0.5f*t2, ty2 = t1 + 0.5f*t3;
            const float area2 = (tx2-tx1)*(ty2-ty1);
            #pragma unroll 4
            for (int it = 0; it < 16; ++it) {
                int q = (it << 6) + lane;
                float val = 0.f;
                if (q < QQ) {
                    float l    = lg[q * CC + lt];
                    float prob = expf(l - s_max[q]) / s_sum[q];
                    float cclass = -prob;
                    float p0 = pb[q*4+0], p1 = pb[q*4+1],
                          p2 = pb[q*4+2], p3 = pb[q*4+3];
                    float cbbox = fabsf(p0-t0) + fabsf(p1-t1)
                                + fabsf(p2-t2) + fabsf(p3-t3);
                    float px1 = p0 - 0.5f*p2, py1 = p1 - 0.5f*p3;
                    float px2 = p0 + 0.5f*p2, py2 = p1 + 0.5f*p3;
                    float area1 = (px2-px1)*(py2-py1);
                    float ltx = fmaxf(px1,tx1), lty = fmaxf(py1,ty1);
                    float rbx = fminf(px2,tx2), rby = fminf(py2,ty2);
                    float wx = fmaxf(rbx-ltx, 0.f), wy = fmaxf(rby-lty, 0.f);
                    float inter = wx*wy;
                    float uni = area1 + area2 - inter;
                    float iou = inter / uni;
                    float cx1 = fminf(px1,tx1), cy1 = fminf(py1,ty1);
                    float cx2 = fmaxf(px2,tx2), cy2 = fmaxf(py2,ty2);
                    float cwx = fmaxf(cx2-cx1, 0.f), cwy = fmaxf(cy2-cy1, 0.f);
                    float areac = cwx*cwy;
                    float giou = iou - (areac - uni) / areac;
                    val = 5.f*cbbox + 1.f*cclass + 2.f*(-giou);
                }
                s_cost[t * RSTRIDE + q] = val;
            }
            asm volatile("s_waitcnt lgkmcnt(0)" ::: "memory");
            if (lane == 0) s_flag[t] = 1;
        }
    } else {
        for (int j = lane; j <= QQ; j += 64) { s_p[j] = 0; s_v[j] = 0.0; }
        if (lane <= NP) s_u[lane] = 0.0;
        asm volatile("s_waitcnt lgkmcnt(0)" ::: "memory");

        int acol = 0;
        const float4* cbase4 = (const float4*)s_cost;

        double vreg[16];
        #pragma unroll
        for (int k = 0; k < 16; ++k) vreg[k] = 0.0;

        unsigned used0 = 0;
        #pragma unroll
        for (int k = 0; k < 16; ++k) {
            int col = 4 * lane + ((k >> 2) << 8) + (k & 3) + 1;
            if (col > QQ) used0 |= 1u << k;
        }

        int nv = 0;
        for (int i = 1; i <= NP; ++i) {
            while (nv < i) {
                if (s_flag[nv]) ++nv;
                else __builtin_amdgcn_s_sleep(2);
            }
            unsigned used = used0;
            int i0 = i, j1prev = 0, T = 0;
            int path_reg = 1, row_reg = 1;
            float4 cf[4];
            {
                const float4* crow4 = cbase4 + (size_t)(i0 - 1) * (RSTRIDE / 4);
                #pragma unroll
                for (int k = 0; k < 4; ++k) cf[k] = crow4[lane + (k << 6)];
            }
            for (int t = 1;; ++t) {
                if (lane == t) row_reg = i0;
                if (j1prev) {
                    int qp = j1prev - 1;
                    if (((qp >> 2) & 63) == lane)
                        used |= 1u << (((qp >> 8) << 2) | (qp & 3));
                }
                double key[16];
                #pragma unroll
                for (int k = 0; k < 4; ++k) {
                    const float* cp = (const float*)&cf[k];
                    #pragma unroll
                    for (int e2 = 0; e2 < 4; ++e2) {
                        int kk  = 4 * k + e2;
                        int col = 4 * lane + (k << 8) + e2 + 1;
                        double d = (double)cp[e2] - vreg[kk];
                        long long bits =
                            (__double_as_longlong(d) & ~2047LL) | (long long)col;
                        key[kk] = ((used >> kk) & 1u)
                                      ? 1e300 : __longlong_as_double(bits);
                    }
                }
                double a0 = fmin(key[0], key[1]),   a1 = fmin(key[2], key[3]);
                double a2 = fmin(key[4], key[5]),   a3 = fmin(key[6], key[7]);
                double a4 = fmin(key[8], key[9]),   a5 = fmin(key[10], key[11]);
                double a6 = fmin(key[12], key[13]), a7 = fmin(key[14], key[15]);
                double b0 = fmin(a0, a1), b1 = fmin(a2, a3);
                double b2 = fmin(a4, a5), b3 = fmin(a6, a7);
                double m  = fmin(fmin(b0, b1), fmin(b2, b3));
                DPP_MIN64(0x111); DPP_MIN64(0x112); DPP_MIN64(0x114);
                DPP_MIN64(0x118); DPP_MIN64(0x142); DPP_MIN64(0x143);
                int wlo = __builtin_amdgcn_readlane((int)__double_as_longlong(m), 63);
                int j1  = wlo & 2047;
                if (lane == t) path_reg = j1;
                unsigned long long mask = __ballot(acol == j1);
                if (mask == 0) { T = t; break; }
                int L = (int)__builtin_ctzll(mask);
                i0 = L + 1;
                j1prev = j1;
                const float4* crow4 = cbase4 + (size_t)L * (RSTRIDE / 4);
                #pragma unroll
                for (int k = 0; k < 4; ++k) cf[k] = crow4[lane + (k << 6)];
            }
            const int  rt  = row_reg;
            const int  myj = path_reg;
            const bool act = (lane >= 1 && lane <= T);
            double mydelta = 0.0, uu = 0.0, vv = 0.0;
            if (act) {
                double cD = (double)s_cost[(rt - 1) * RSTRIDE + (myj - 1)];
                mydelta = (cD - s_u[rt]) - s_v[myj];
                uu = s_u[rt];
                vv = s_v[myj];
            }
            for (int s = 1; s <= T; ++s) {
                double ds = readlane_dbl(mydelta, s);
                int    js = __builtin_amdgcn_readlane(path_reg, s);
                int    rs = __builtin_amdgcn_readlane(row_reg, s);
                if (lane >= 1 && lane <= s) uu += ds;
                if (lane >= 1 && lane <  s) vv -= ds;
                if (rs == lane + 1) acol = js;
            }
            if (act) {
                s_u[rt]  = uu;
                s_v[myj] = vv;
                s_p[myj] = rt;
            }
            for (int s = 1; s <= T; ++s) {
                int    js  = __builtin_amdgcn_readlane(path_reg, s);
                double vvs = readlane_dbl(vv, s);
                #pragma unroll
                for (int k = 0; k < 16; ++k) {
                    int col = 4 * lane + ((k >> 2) << 8) + (k & 3) + 1;
                    if (col == js) vreg[k] = vvs;
                }
            }
        }
    }
    __syncthreads();

    for (int e = tid; e < QQ * 8; e += NT) {
        int q = e >> 3;
        int f = e & 7;
        int pq = s_p[q + 1];
        int base = 4 * f;
        float4 o;
        o.x = (pq == base + 1) ? 1.f : 0.f;
        o.y = (pq == base + 2) ? 1.f : 0.f;
        o.z = (pq == base + 3) ? 1.f : 0.f;
        o.w = (pq == base + 4) ? 1.f : 0.f;
        ((float4*)(out + (size_t)q * TT + b * NP))[f] = o;
    }
}

// ---------------------------------------------------------------------------
extern "C" void kernel_launch(void* const* d_in, const int* in_sizes, int n_in,
                              void* d_out, int out_size, void* d_ws, size_t ws_size,
                              hipStream_t stream) {
    const float* logits = (const float*)d_in[0];   // (16,900,92)
    const float* pboxes = (const float*)d_in[1];   // (16,900,4)
    const int*   labels = (const int*)  d_in[2];   // (512,)
    const float* tboxes = (const float*)d_in[3];   // (512,4)
    float* out = (float*)d_out;                    // (900,512) fp32

    if (d_ws != nullptr && ws_size >= (size_t)WS_NEED) {
        float* wcost = (float*)((char*)d_ws + WSC_COST);
        float* wmax  = (float*)((char*)d_ws + WSC_MAX);
        float* wsum  = (float*)((char*)d_ws + WSC_SUM);
        int*   wa    = (int*)  ((char*)d_ws + WSC_A);

        (void)hipFuncSetAttribute((const void*)walk_kernel,
                                  hipFuncAttributeMaxDynamicSharedMemorySize,
                                  C_DYN);

        denom_kernel<<<(BB*QQ + 255)/256, 256, 0, stream>>>(logits, wmax, wsum);
        cost_kernel<<<BB*NP, 256, 0, stream>>>(logits, pboxes, labels, tboxes,
                                               wmax, wsum, wcost);
        walk_kernel<<<BB, 256, C_DYN, stream>>>(wcost, wa);
        epilogue_kernel<<<(QQ*BB*8 + 255)/256, 256, 0, stream>>>(wa, out);
    } else {
        (void)hipFuncSetAttribute((const void*)matcher_kernel,
                                  hipFuncAttributeMaxDynamicSharedMemorySize,
                                  DYN_BYTES);
        matcher_kernel<<<BB, NT, DYN_BYTES, stream>>>(logits, pboxes, labels,
                                                      tboxes, out);
    }
}

// Round 6
// 98.810 us; speedup vs baseline: 1.7046x; 1.0656x over previous
//
#include <hip/hip_runtime.h>
#include <math.h>

#define BB 16
#define QQ 900
#define CC 92
#define NP 32
#define TT (BB*NP)     // 512
#define RSTRIDE 1024   // cost row stride (floats)
#define NT 512         // monolithic fallback: 8 waves/block

// ---------------------------------------------------------------------------
// Workspace layout (bytes)
#define WSC_COST 0
#define WSC_MAX  (BB*NP*RSTRIDE*4)          // 512 rows * 4KB = 2097152
#define WSC_SUM  (WSC_MAX + BB*QQ*4)        // + 57600
#define WSC_A    (WSC_SUM + BB*QQ*4)        // + 57600 (wa slot retained, unused)
#define WS_NEED  (WSC_A + TT*4)             // + 2048 = 2214400

// ---------------------------------------------------------------------------
__device__ __forceinline__ double mkdbl(int lo, int hi) {
    return __longlong_as_double(((long long)hi << 32) | (unsigned int)lo);
}
__device__ __forceinline__ double readlane_dbl(double x, int s) {
    long long l = __double_as_longlong(x);
    int lo = __builtin_amdgcn_readlane((int)l, s);
    int hi = __builtin_amdgcn_readlane((int)(l >> 32), s);
    return mkdbl(lo, hi);
}
// per-lane gather: result lane gets x from lane srclane (ds_bpermute, 2x b32)
__device__ __forceinline__ double bpermute_dbl(int srclane, double x) {
    long long l = __double_as_longlong(x);
    int lo = __builtin_amdgcn_ds_bpermute(srclane << 2, (int)l);
    int hi = __builtin_amdgcn_ds_bpermute(srclane << 2, (int)(l >> 32));
    return mkdbl(lo, hi);
}

// fp64 DPP min step (2 dpp movs + v_min_f64); row_shr:1/2/4/8 + row_bcast:15/31
// leaves the global min in lane 63 (HW-verified rounds 5-9, absmax=0).
#define DPP_MIN64(CTRL)                                                       \
    {                                                                         \
        long long _l = __double_as_longlong(m);                               \
        int _lo = (int)_l, _hi = (int)(_l >> 32);                             \
        int _olo = __builtin_amdgcn_update_dpp(_lo, _lo, CTRL, 0xf, 0xf, false); \
        int _ohi = __builtin_amdgcn_update_dpp(_hi, _hi, CTRL, 0xf, 0xf, false); \
        m = fmin(m, mkdbl(_olo, _ohi));                                       \
    }

// ===========================================================================
// Kernel A: softmax denominators, full chip. One thread per (b,q) row;
// per-row FP chain byte-identical to the monolithic softmax loop.
__launch_bounds__(256)
__global__ void denom_kernel(const float* __restrict__ logits,
                             float* __restrict__ wmax,
                             float* __restrict__ wsum)
{
    int idx = blockIdx.x * 256 + threadIdx.x;
    if (idx >= BB * QQ) return;
    const float4* row4 = (const float4*)(logits + (size_t)idx * CC);
    float mx = -INFINITY;
    #pragma unroll
    for (int k = 0; k < 23; ++k) {
        float4 x = row4[k];
        mx = fmaxf(mx, x.x); mx = fmaxf(mx, x.y);
        mx = fmaxf(mx, x.z); mx = fmaxf(mx, x.w);
    }
    float s = 0.f;
    #pragma unroll
    for (int k = 0; k < 23; ++k) {
        float4 x = row4[k];
        s += expf(x.x - mx); s += expf(x.y - mx);
        s += expf(x.z - mx); s += expf(x.w - mx);
    }
    wmax[idx] = mx;
    wsum[idx] = s;
}

// ===========================================================================
// Kernel B: cost rows, full chip. One block per (b,t); per-element FP
// formula byte-identical to rounds 2-15. Pads q in [900,1024) = 0.
__launch_bounds__(256)
__global__ void cost_kernel(const float* __restrict__ logits,
                            const float* __restrict__ pboxes,
                            const int*   __restrict__ labels,
                            const float* __restrict__ tboxes,
                            const float* __restrict__ wmax,
                            const float* __restrict__ wsum,
                            float* __restrict__ wcost)
{
    const int r = blockIdx.x;          // 0..511 = b*NP + t
    const int b = r >> 5, t = r & 31;
    const float* lg = logits + (size_t)b * QQ * CC;
    const float* pb = pboxes + (size_t)b * QQ * 4;
    const float* tb = tboxes + (size_t)b * NP * 4;
    const float* smax = wmax + b * QQ;
    const float* ssum = wsum + b * QQ;

    const float t0 = tb[t*4+0], t1 = tb[t*4+1], t2 = tb[t*4+2], t3 = tb[t*4+3];
    const int   lt = labels[b * NP + t];
    const float tx1 = t0 - 0.5f*t2, ty1 = t1 - 0.5f*t3;
    const float tx2 = t0 + 0.5f*t2, ty2 = t1 + 0.5f*t3;
    const float area2 = (tx2-tx1)*(ty2-ty1);

    float* crow = wcost + (size_t)r * RSTRIDE;
    for (int q = threadIdx.x; q < RSTRIDE; q += 256) {
        float val = 0.f;
        if (q < QQ) {
            float l    = lg[q * CC + lt];
            float prob = expf(l - smax[q]) / ssum[q];
            float cclass = -prob;
            float p0 = pb[q*4+0], p1 = pb[q*4+1], p2 = pb[q*4+2], p3 = pb[q*4+3];
            float cbbox = fabsf(p0-t0) + fabsf(p1-t1)
                        + fabsf(p2-t2) + fabsf(p3-t3);
            float px1 = p0 - 0.5f*p2, py1 = p1 - 0.5f*p3;
            float px2 = p0 + 0.5f*p2, py2 = p1 + 0.5f*p3;
            float area1 = (px2-px1)*(py2-py1);
            float ltx = fmaxf(px1,tx1), lty = fmaxf(py1,ty1);
            float rbx = fminf(px2,tx2), rby = fminf(py2,ty2);
            float wx = fmaxf(rbx-ltx, 0.f), wy = fmaxf(rby-lty, 0.f);
            float inter = wx*wy;
            float uni = area1 + area2 - inter;
            float iou = inter / uni;
            float cx1 = fminf(px1,tx1), cy1 = fminf(py1,ty1);
            float cx2 = fmaxf(px2,tx2), cy2 = fmaxf(py2,ty2);
            float cwx = fmaxf(cx2-cx1, 0.f), cwy = fmaxf(cy2-cy1, 0.f);
            float areac = cwx*cwy;
            float giou = iou - (areac - uni) / areac;
            val = 5.f*cbbox + 1.f*cclass + 2.f*(-giou);
        }
        crow[q] = val;
    }
}

// ===========================================================================
// Kernel C: serial JV walk + fused epilogue. 16 blocks x 8 waves:
// waves 1-7 stage cost rows ws->LDS round-robin (per-row flags); wave 0
// walks; then ALL waves write the (900 x 32) output tile for batch b.
//
// Round-16 changes (bit-exact):
//  * u[] register-resident: lane r of wave 0 holds u[r] (ureg). Phase-start
//    u0[rt] fetched per-act-lane via ds_bpermute (rt is per-lane). Replay
//    accumulates ureg += d_s for rows in-path (inpath flag set at the row's
//    entry iteration) -- identical left-associated order as the old
//    s_u-based accumulation -> bit-identical.
//  * T==1 fast path: skip vreg mirror and s_v write. For T==1 no j1prev
//    corruption ever happened and the reference only updates dummy v[0]
//    (v[used] -= delta with used={0}) -> real v unchanged. Provable no-op.
//  * epilogue fused (out written here from LDS assignment array).
// Round-15 core retained: vreg exclusion-by-corruption, early-issue loads,
// pre-issue of next phase's first row, packed-col f64 keys, 6-step DPP min.
#define C_OFF_COST 0
#define C_SZ_COST  (NP * RSTRIDE * 4)       // 131072
#define C_OFF_V    (C_OFF_COST + C_SZ_COST) // 901 dbl -> 7208
#define C_OFF_FLAG (C_OFF_V + 7208)         // 32 int  -> 128
#define C_OFF_ASN  (C_OFF_FLAG + 128)       // 32 int  -> 128
#define C_DYN      (C_OFF_ASN + 128)        // 138536  (< 160 KiB)

__launch_bounds__(512)
__global__ void walk_kernel(const float* __restrict__ wcost,
                            float* __restrict__ out)
{
    extern __shared__ char smem[];
    float*  s_cost = (float*)(smem + C_OFF_COST);   // [NP][RSTRIDE]
    double* s_v    = (double*)(smem + C_OFF_V);
    volatile int* s_flag = (volatile int*)(smem + C_OFF_FLAG);
    int*    s_asn  = (int*)(smem + C_OFF_ASN);

    const int b    = blockIdx.x;
    const int tid  = threadIdx.x;
    const int wv   = tid >> 6;
    const int lane = tid & 63;

    if (tid < 32) s_flag[tid] = 0;
    __syncthreads();

    if (wv != 0) {
        // ---- waves 1-7: stage rows round-robin, flag after full drain -----
        for (int t = wv - 1; t < NP; t += 7) {
            const float4* src =
                (const float4*)(wcost + ((size_t)(b * NP + t) * RSTRIDE));
            float4* dst = (float4*)(s_cost + t * RSTRIDE);
            float4 v0 = src[lane];
            float4 v1 = src[lane + 64];
            float4 v2 = src[lane + 128];
            float4 v3 = src[lane + 192];
            dst[lane]       = v0;
            dst[lane + 64]  = v1;
            dst[lane + 128] = v2;
            dst[lane + 192] = v3;
            asm volatile("s_waitcnt vmcnt(0) lgkmcnt(0)" ::: "memory");
            if (lane == 0) s_flag[t] = 1;
        }
    } else {
        // ---- wave 0: init v, then the serial walk -------------------------
        for (int j = lane; j <= QQ; j += 64) s_v[j] = 0.0;
        asm volatile("s_waitcnt lgkmcnt(0)" ::: "memory");

        int acol = 0;                   // lane r-1: column assigned to row r
        double ureg = 0.0;              // lane r: u[r] (lanes 1..32 live)
        const float4* cbase4 = (const float4*)s_cost;  // 256 float4 per row

        // register-resident v in the w layout: vreg[k] = v[col(k)].
        // Pads (col > QQ) held at -1e300 forever (excluded). Written only
        // at phase end -> during a phase it IS the frozen v0 snapshot.
        double vreg[16];
        #pragma unroll
        for (int k = 0; k < 16; ++k) {
            int col = 4 * lane + ((k >> 2) << 8) + (k & 3) + 1;
            vreg[k] = (col <= QQ) ? 0.0 : -1.0e300;
        }

        int nv = 0;                     // rows verified ready (monotone)

        // prologue: wait for row 0, load phase-1's row
        while (nv < 1) {
            if (s_flag[0]) nv = 1;
            else __builtin_amdgcn_s_sleep(2);
        }
        float4 cf[4];
        {
            const float4* crow4 = cbase4;   // row 0
            #pragma unroll
            for (int k = 0; k < 4; ++k) cf[k] = crow4[lane + (k << 6)];
        }

        for (int i = 1; i <= NP; ++i) {
            // cf already holds row i-1 (phase's starting row)
            int i0 = i, j1prev = 0, T = 0;
            int path_reg = 1, row_reg = 1;

            for (int t = 1;; ++t) {
                if (lane == t) row_reg = i0;      // writelane (i0 uniform)
                // mark previous winner used by corrupting its vreg slot to
                // -1e300 (wave-uniform branch). Repaired by the phase-end
                // mirror (j1prev cols are path cols).
                if (j1prev) {
                    #pragma unroll
                    for (int k = 0; k < 16; ++k) {
                        int col = 4 * lane + ((k >> 2) << 8) + (k & 3) + 1;
                        if (col == j1prev) vreg[k] = -1.0e300;
                    }
                }

                // keys: (c - v0[j]) packed with col in low 11 bits; excluded
                // slots give finite ~+1e300..DBL_MAX -> never the min
                double key[16];
                #pragma unroll
                for (int k = 0; k < 4; ++k) {
                    const float* cp = (const float*)&cf[k];
                    #pragma unroll
                    for (int e2 = 0; e2 < 4; ++e2) {
                        int kk  = 4 * k + e2;
                        int col = 4 * lane + (k << 8) + e2 + 1;
                        double d = (double)cp[e2] - vreg[kk];
                        long long bits =
                            (__double_as_longlong(d) & ~2047LL) | (long long)col;
                        key[kk] = __longlong_as_double(bits);
                    }
                }
                // in-lane 16-way min tree (pure v_min_f64)
                double a0 = fmin(key[0], key[1]),   a1 = fmin(key[2], key[3]);
                double a2 = fmin(key[4], key[5]),   a3 = fmin(key[6], key[7]);
                double a4 = fmin(key[8], key[9]),   a5 = fmin(key[10], key[11]);
                double a6 = fmin(key[12], key[13]), a7 = fmin(key[14], key[15]);
                double b0 = fmin(a0, a1), b1 = fmin(a2, a3);
                double b2 = fmin(a4, a5), b3 = fmin(a6, a7);
                double m  = fmin(fmin(b0, b1), fmin(b2, b3));

                DPP_MIN64(0x111);  // row_shr:1
                DPP_MIN64(0x112);  // row_shr:2
                DPP_MIN64(0x114);  // row_shr:4
                DPP_MIN64(0x118);  // row_shr:8
                DPP_MIN64(0x142);  // row_bcast:15
                DPP_MIN64(0x143);  // row_bcast:31

                int wlo = __builtin_amdgcn_readlane((int)__double_as_longlong(m), 63);
                int j1  = wlo & 2047;

                if (lane == t) path_reg = j1;     // writelane (j1 uniform)

                // p[j1] via ballot over register-resident assignment map
                unsigned long long mask = __ballot(acol == j1);
                if (mask == 0) { T = t; break; }
                int L = (int)__builtin_ctzll(mask);
                i0 = L + 1;
                j1prev = j1;

                // EARLY ISSUE: next row's loads, before next iter's marking
                const float4* crow4 = cbase4 + (size_t)L * (RSTRIDE / 4);
                #pragma unroll
                for (int k = 0; k < 4; ++k) cf[k] = crow4[lane + (k << 6)];
            }

            // ---- pre-issue next phase's row (index i) if already staged ---
            bool pre = false;
            if (i < NP) {
                if (nv > i) pre = true;
                else if (s_flag[25] && s_flag[26] && s_flag[27] && s_flag[28]
                      && s_flag[29] && s_flag[30] && s_flag[31]) {
                    nv = NP;    // 7-wave round-robin: last row of each wave
                    pre = true;
                }
                if (pre) {
                    const float4* crow4 = cbase4 + (size_t)i * (RSTRIDE / 4);
                    #pragma unroll
                    for (int k = 0; k < 4; ++k) cf[k] = crow4[lane + (k << 6)];
                }
            }

            // ---- phase end: exact ordered replay (lanes 1..T hold r_t,j_t)
            const int  rt  = row_reg;
            const int  myj = path_reg;
            const bool act = (lane >= 1 && lane <= T);
            double mydelta = 0.0, vv = 0.0;
            {
                double cD = 0.0, v0j = 0.0;
                if (act) {
                    cD  = (double)s_cost[(rt - 1) * RSTRIDE + (myj - 1)];
                    v0j = s_v[myj];
                }
                double u0rt = bpermute_dbl(rt, ureg);   // phase-start u[rt]
                if (act) {
                    mydelta = (cD - u0rt) - v0j;        // exact ref op order
                    vv = v0j;
                }
            }
            bool inpath = false;
            for (int s = 1; s <= T; ++s) {
                double ds = readlane_dbl(mydelta, s);
                int    js = __builtin_amdgcn_readlane(path_reg, s);
                int    rs = __builtin_amdgcn_readlane(row_reg, s);
                if (lane + 1 == rs) inpath = true;      // row enters at s
                if (inpath) ureg += ds;                 // u[r_t] += d_t..d_T
                if (lane >= 1 && lane <  s) vv -= ds;   // v[j_t] -= d_{t+1}..
                if (rs == lane + 1) acol = js;          // row r_s -> col j_s
            }
            if (T > 1) {
                if (act) s_v[myj] = vv;
                // mirror v updates into vreg (repairs corrupted slots)
                for (int s = 1; s <= T; ++s) {
                    int    js  = __builtin_amdgcn_readlane(path_reg, s);
                    double vvs = readlane_dbl(vv, s);
                    #pragma unroll
                    for (int k = 0; k < 16; ++k) {
                        int col = 4 * lane + ((k >> 2) << 8) + (k & 3) + 1;
                        if (col == js) vreg[k] = vvs;
                    }
                }
            }
            // T==1: no corruption happened, v unchanged (ref touches only
            // dummy v[0]) -> mirror and s_v write skipped.

            // ---- deferred load path (row i not staged at pre-check) -------
            if (i < NP && !pre) {
                while (nv <= i) {
                    if (s_flag[nv]) ++nv;
                    else __builtin_amdgcn_s_sleep(2);
                }
                const float4* crow4 = cbase4 + (size_t)i * (RSTRIDE / 4);
                #pragma unroll
                for (int k = 0; k < 4; ++k) cf[k] = crow4[lane + (k << 6)];
            }
        }

        // lanes 0..31 hold acol = 1-based column of row lane+1
        if (lane < NP) s_asn[lane] = acol - 1;
    }
    __syncthreads();

    // ---- fused epilogue: full (900 x 32) tile, float4 stores --------------
    for (int e = tid; e < QQ * 8; e += 512) {
        int q = e >> 3;
        int f = e & 7;
        int base = 4 * f;
        int a0 = s_asn[base + 0], a1 = s_asn[base + 1];
        int a2 = s_asn[base + 2], a3 = s_asn[base + 3];
        float4 o;
        o.x = (a0 == q) ? 1.f : 0.f;
        o.y = (a1 == q) ? 1.f : 0.f;
        o.z = (a2 == q) ? 1.f : 0.f;
        o.w = (a3 == q) ? 1.f : 0.f;
        ((float4*)(out + (size_t)q * TT + b * NP))[f] = o;
    }
}

// ===========================================================================
// Fallback: the round-13 monolithic kernel, verbatim (used if ws too small).
#define OFF_COST 0
#define SZ_COST  (NP * RSTRIDE * 4)        // 131072
#define OFF_U    (OFF_COST + SZ_COST)      // 33 dbl  -> 264
#define OFF_V    (OFF_U + 264)             // 901 dbl -> 7208
#define OFF_P    (OFF_V + 7208)            // 901 int -> 3604
#define OFF_MAX  (OFF_P + 3604)            // 900 f   -> 3600
#define OFF_SUM  (OFF_MAX + 3600)          // 900 f   -> 3600
#define OFF_FLAG (OFF_SUM + 3600)          // 32 int  -> 128
#define DYN_BYTES (OFF_FLAG + 128)         // 149476  (< 160 KiB)

__launch_bounds__(NT)
__global__ void matcher_kernel(const float* __restrict__ logits,
                               const float* __restrict__ pboxes,
                               const int*   __restrict__ labels,
                               const float* __restrict__ tboxes,
                               float* __restrict__ out)
{
    extern __shared__ char smem[];
    float*  s_cost = (float*)(smem + OFF_COST);
    double* s_u    = (double*)(smem + OFF_U);
    double* s_v    = (double*)(smem + OFF_V);
    int*    s_p    = (int*)(smem + OFF_P);
    float*  s_max  = (float*)(smem + OFF_MAX);
    float*  s_sum  = (float*)(smem + OFF_SUM);
    volatile int* s_flag = (volatile int*)(smem + OFF_FLAG);

    const int b    = blockIdx.x;
    const int tid  = threadIdx.x;
    const int wv   = tid >> 6;
    const int lane = tid & 63;

    const float* lg = logits + (size_t)b * QQ * CC;
    if (tid < 32) s_flag[tid] = 0;
    for (int q = tid; q < QQ; q += NT) {
        const float4* row4 = (const float4*)(lg + q * CC);
        float mx = -INFINITY;
        #pragma unroll
        for (int k = 0; k < 23; ++k) {
            float4 x = row4[k];
            mx = fmaxf(mx, x.x); mx = fmaxf(mx, x.y);
            mx = fmaxf(mx, x.z); mx = fmaxf(mx, x.w);
        }
        float s = 0.f;
        #pragma unroll
        for (int k = 0; k < 23; ++k) {
            float4 x = row4[k];
            s += expf(x.x - mx); s += expf(x.y - mx);
            s += expf(x.z - mx); s += expf(x.w - mx);
        }
        s_max[q] = mx;
        s_sum[q] = s;
    }
    __syncthreads();

    const float* pb = pboxes + (size_t)b * QQ * 4;
    const float* tb = tboxes + (size_t)b * NP * 4;
    const int*   lb = labels + b * NP;

    if (wv != 0) {
        for (int t = wv - 1; t < NP; t += 7) {
            const float t0 = tb[t*4+0], t1 = tb[t*4+1],
                        t2 = tb[t*4+2], t3 = tb[t*4+3];
            const int   lt = lb[t];
            const float tx1 = t0 - 0.5f*t2, ty1 = t1 - 0.5f*t3;
            const float tx2 = t0 + 0.5f*t2, ty2 = t1 + 0.5f*t3;
            const float area2 = (tx2-tx1)*(ty2-ty1);
            #pragma unroll 4
            for (int it = 0; it < 16; ++it) {
                int q = (it << 6) + lane;
                float val = 0.f;
                if (q < QQ) {
                    float l    = lg[q * CC + lt];
                    float prob = expf(l - s_max[q]) / s_sum[q];
                    float cclass = -prob;
                    float p0 = pb[q*4+0], p1 = pb[q*4+1],
                          p2 = pb[q*4+2], p3 = pb[q*4+3];
                    float cbbox = fabsf(p0-t0) + fabsf(p1-t1)
                                + fabsf(p2-t2) + fabsf(p3-t3);
                    float px1 = p0 - 0.5f*p2, py1 = p1 - 0.5f*p3;
                    float px2 = p0 + 0.5f*p2, py2 = p1 + 0.5f*p3;
                    float area1 = (px2-px1)*(py2-py1);
                    float ltx = fmaxf(px1,tx1), lty = fmaxf(py1,ty1);
                    float rbx = fminf(px2,tx2), rby = fminf(py2,ty2);
                    float wx = fmaxf(rbx-ltx, 0.f), wy = fmaxf(rby-lty, 0.f);
                    float inter = wx*wy;
                    float uni = area1 + area2 - inter;
                    float iou = inter / uni;
                    float cx1 = fminf(px1,tx1), cy1 = fminf(py1,ty1);
                    float cx2 = fmaxf(px2,tx2), cy2 = fmaxf(py2,ty2);
                    float cwx = fmaxf(cx2-cx1, 0.f), cwy = fmaxf(cy2-cy1, 0.f);
                    float areac = cwx*cwy;
                    float giou = iou - (areac - uni) / areac;
                    val = 5.f*cbbox + 1.f*cclass + 2.f*(-giou);
                }
                s_cost[t * RSTRIDE + q] = val;
            }
            asm volatile("s_waitcnt lgkmcnt(0)" ::: "memory");
            if (lane == 0) s_flag[t] = 1;
        }
    } else {
        for (int j = lane; j <= QQ; j += 64) { s_p[j] = 0; s_v[j] = 0.0; }
        if (lane <= NP) s_u[lane] = 0.0;
        asm volatile("s_waitcnt lgkmcnt(0)" ::: "memory");

        int acol = 0;
        const float4* cbase4 = (const float4*)s_cost;

        double vreg[16];
        #pragma unroll
        for (int k = 0; k < 16; ++k) vreg[k] = 0.0;

        unsigned used0 = 0;
        #pragma unroll
        for (int k = 0; k < 16; ++k) {
            int col = 4 * lane + ((k >> 2) << 8) + (k & 3) + 1;
            if (col > QQ) used0 |= 1u << k;
        }

        int nv = 0;
        for (int i = 1; i <= NP; ++i) {
            while (nv < i) {
                if (s_flag[nv]) ++nv;
                else __builtin_amdgcn_s_sleep(2);
            }
            unsigned used = used0;
            int i0 = i, j1prev = 0, T = 0;
            int path_reg = 1, row_reg = 1;
            float4 cf[4];
            {
                const float4* crow4 = cbase4 + (size_t)(i0 - 1) * (RSTRIDE / 4);
                #pragma unroll
                for (int k = 0; k < 4; ++k) cf[k] = crow4[lane + (k << 6)];
            }
            for (int t = 1;; ++t) {
                if (lane == t) row_reg = i0;
                if (j1prev) {
                    int qp = j1prev - 1;
                    if (((qp >> 2) & 63) == lane)
                        used |= 1u << (((qp >> 8) << 2) | (qp & 3));
                }
                double key[16];
                #pragma unroll
                for (int k = 0; k < 4; ++k) {
                    const float* cp = (const float*)&cf[k];
                    #pragma unroll
                    for (int e2 = 0; e2 < 4; ++e2) {
                        int kk  = 4 * k + e2;
                        int col = 4 * lane + (k << 8) + e2 + 1;
                        double d = (double)cp[e2] - vreg[kk];
                        long long bits =
                            (__double_as_longlong(d) & ~2047LL) | (long long)col;
                        key[kk] = ((used >> kk) & 1u)
                                      ? 1e300 : __longlong_as_double(bits);
                    }
                }
                double a0 = fmin(key[0], key[1]),   a1 = fmin(key[2], key[3]);
                double a2 = fmin(key[4], key[5]),   a3 = fmin(key[6], key[7]);
                double a4 = fmin(key[8], key[9]),   a5 = fmin(key[10], key[11]);
                double a6 = fmin(key[12], key[13]), a7 = fmin(key[14], key[15]);
                double b0 = fmin(a0, a1), b1 = fmin(a2, a3);
                double b2 = fmin(a4, a5), b3 = fmin(a6, a7);
                double m  = fmin(fmin(b0, b1), fmin(b2, b3));
                DPP_MIN64(0x111); DPP_MIN64(0x112); DPP_MIN64(0x114);
                DPP_MIN64(0x118); DPP_MIN64(0x142); DPP_MIN64(0x143);
                int wlo = __builtin_amdgcn_readlane((int)__double_as_longlong(m), 63);
                int j1  = wlo & 2047;
                if (lane == t) path_reg = j1;
                unsigned long long mask = __ballot(acol == j1);
                if (mask == 0) { T = t; break; }
                int L = (int)__builtin_ctzll(mask);
                i0 = L + 1;
                j1prev = j1;
                const float4* crow4 = cbase4 + (size_t)L * (RSTRIDE / 4);
                #pragma unroll
                for (int k = 0; k < 4; ++k) cf[k] = crow4[lane + (k << 6)];
            }
            const int  rt  = row_reg;
            const int  myj = path_reg;
            const bool act = (lane >= 1 && lane <= T);
            double mydelta = 0.0, uu = 0.0, vv = 0.0;
            if (act) {
                double cD = (double)s_cost[(rt - 1) * RSTRIDE + (myj - 1)];
                mydelta = (cD - s_u[rt]) - s_v[myj];
                uu = s_u[rt];
                vv = s_v[myj];
            }
            for (int s = 1; s <= T; ++s) {
                double ds = readlane_dbl(mydelta, s);
                int    js = __builtin_amdgcn_readlane(path_reg, s);
                int    rs = __builtin_amdgcn_readlane(row_reg, s);
                if (lane >= 1 && lane <= s) uu += ds;
                if (lane >= 1 && lane <  s) vv -= ds;
                if (rs == lane + 1) acol = js;
            }
            if (act) {
                s_u[rt]  = uu;
                s_v[myj] = vv;
                s_p[myj] = rt;
            }
            for (int s = 1; s <= T; ++s) {
                int    js  = __builtin_amdgcn_readlane(path_reg, s);
                double vvs = readlane_dbl(vv, s);
                #pragma unroll
                for (int k = 0; k < 16; ++k) {
                    int col = 4 * lane + ((k >> 2) << 8) + (k & 3) + 1;
                    if (col == js) vreg[k] = vvs;
                }
            }
        }
    }
    __syncthreads();

    for (int e = tid; e < QQ * 8; e += NT) {
        int q = e >> 3;
        int f = e & 7;
        int pq = s_p[q + 1];
        int base = 4 * f;
        float4 o;
        o.x = (pq == base + 1) ? 1.f : 0.f;
        o.y = (pq == base + 2) ? 1.f : 0.f;
        o.z = (pq == base + 3) ? 1.f : 0.f;
        o.w = (pq == base + 4) ? 1.f : 0.f;
        ((float4*)(out + (size_t)q * TT + b * NP))[f] = o;
    }
}

// ---------------------------------------------------------------------------
extern "C" void kernel_launch(void* const* d_in, const int* in_sizes, int n_in,
                              void* d_out, int out_size, void* d_ws, size_t ws_size,
                              hipStream_t stream) {
    const float* logits = (const float*)d_in[0];   // (16,900,92)
    const float* pboxes = (const float*)d_in[1];   // (16,900,4)
    const int*   labels = (const int*)  d_in[2];   // (512,)
    const float* tboxes = (const float*)d_in[3];   // (512,4)
    float* out = (float*)d_out;                    // (900,512) fp32

    if (d_ws != nullptr && ws_size >= (size_t)WS_NEED) {
        float* wcost = (float*)((char*)d_ws + WSC_COST);
        float* wmax  = (float*)((char*)d_ws + WSC_MAX);
        float* wsum  = (float*)((char*)d_ws + WSC_SUM);

        (void)hipFuncSetAttribute((const void*)walk_kernel,
                                  hipFuncAttributeMaxDynamicSharedMemorySize,
                                  C_DYN);

        denom_kernel<<<(BB*QQ + 255)/256, 256, 0, stream>>>(logits, wmax, wsum);
        cost_kernel<<<BB*NP, 256, 0, stream>>>(logits, pboxes, labels, tboxes,
                                               wmax, wsum, wcost);
        walk_kernel<<<BB, 512, C_DYN, stream>>>(wcost, out);
    } else {
        (void)hipFuncSetAttribute((const void*)matcher_kernel,
                                  hipFuncAttributeMaxDynamicSharedMemorySize,
                                  DYN_BYTES);
        matcher_kernel<<<BB, NT, DYN_BYTES, stream>>>(logits, pboxes, labels,
                                                      tboxes, out);
    }
}